// Round 1
// baseline (372.234 us; speedup 1.0000x reference)
//
#include <hip/hip_runtime.h>

// Inputs: floats fp32, ints int32. Outputs fp32 (verified round 7).
// Round 17: launch-count collapse 13 -> 7 dispatches.
//   - k_prep + k_ln1 + deg-zero fused (role-split grid); memset dropped.
//   - k_chunksum/k_chunkscan/k_cursor/k_bscan -> one single-block scan kernel.
//   - k_aggcsr + k_gemm fused; mean goes straight to LDS A-tile (no meanb
//     roundtrip). 4-rows-per-load gather (16 lanes x 16B per row).
//   - h3 now written to h3b (old meanb slot) -- hb stays read-only during
//     the fused agg+gemm kernel (gather race avoided).

typedef unsigned short ushort_t;
typedef __attribute__((ext_vector_type(8))) short bf16x8;   // 8 bf16 (MFMA A/B frag)
typedef __attribute__((ext_vector_type(4))) float floatx4;  // MFMA C/D frag

#define NBLK 128      // edge chunks for hist/place
#define MAXNB 1024    // max buckets (N <= 131072)

// ---------- helpers ----------
__device__ __forceinline__ float b2f(ushort_t u) {
    union { unsigned int i; float f; } v; v.i = ((unsigned int)u) << 16; return v.f;
}
__device__ __forceinline__ ushort_t f2b(float f) {
    union { float f; unsigned int i; } v; v.f = f;
    unsigned int x = v.i;
    return (ushort_t)((x + 0x7FFFu + ((x >> 16) & 1u)) >> 16);   // RTNE
}
__device__ __forceinline__ float gelu_f(float x) {
    return 0.5f * x * (1.0f + erff(x * 0.70710678118654752440f)); // exact gelu
}
__device__ __forceinline__ float waveReduceSum(float v) {
#pragma unroll
    for (int o = 32; o; o >>= 1) v += __shfl_xor(v, o, 64);
    return v;
}
__device__ __forceinline__ float waveReduceMax(float v) {
#pragma unroll
    for (int o = 32; o; o >>= 1) v = fmaxf(v, __shfl_xor(v, o, 64));
    return v;
}
__device__ __forceinline__ int lowerBound(const int* __restrict__ a, int n, int v) {
    int lo = 0, hi = n;
    while (lo < hi) { int mid = (lo + hi) >> 1; if (a[mid] < v) lo = mid + 1; else hi = mid; }
    return lo;
}

// ---------- 1. fused: Wt prep (blocks 0..127) | LN1 + deg-zero (rest) ----------
__global__ void __launch_bounds__(256) k_prepln(
    const float* __restrict__ x, const float* __restrict__ w, const float* __restrict__ b,
    const float* __restrict__ Wl, const float* __restrict__ Wr,
    ushort_t* __restrict__ Wt, ushort_t* __restrict__ hb, int* __restrict__ deg, int N) {
    int bid = blockIdx.x;
    if (bid < 128) {             // ---- prep role: Wt[n][k] = bf16 concat-T of Wl;Wr
        int id = bid * 256 + threadIdx.x;        // exactly 32768 threads
        int n = id >> 8, k = id & 255;
        float v = (k < 128) ? Wl[k * 128 + n] : Wr[(k - 128) * 128 + n];
        Wt[n * 256 + k] = f2b(v);
        return;
    }
    int lb = bid - 128;          // ---- ln1 role: 4 rows per block, 1 wave per row
    if (threadIdx.x < 4) {       // zero deg for this block's rows (replaces memset)
        int rz = lb * 4 + threadIdx.x;
        if (rz < N) deg[rz] = 0;
    }
    int row  = lb * 4 + (threadIdx.x >> 6);
    int lane = threadIdx.x & 63;
    if (row >= N) return;
    size_t base = (size_t)row * 128;
    float2 xv = ((const float2*)(x + base))[lane];
    float v0 = xv.x, v1 = xv.y;
    float s  = waveReduceSum(v0 + v1);
    float s2 = waveReduceSum(v0 * v0 + v1 * v1);
    float mu = s * (1.0f / 128.0f);
    float var = s2 * (1.0f / 128.0f) - mu * mu;
    float rstd = 1.0f / sqrtf(var + 1e-5f);
    int d = lane * 2;
    ushort2 ov;
    ov.x = f2b((v0 - mu) * rstd * w[d]     + b[d]);
    ov.y = f2b((v1 - mu) * rstd * w[d + 1] + b[d + 1]);
    ((ushort2*)(hb + base))[lane] = ov;
}

// ---------- 2. fused: deg[dst]++ (global) + per-chunk bucket hist (LDS) ----------
__global__ void __launch_bounds__(256) k_deghist(
    const int* __restrict__ ei, int* __restrict__ deg, int* __restrict__ bhist,
    int E, int nb, int chunk) {
    __shared__ int hist[MAXNB];
    int blk = blockIdx.x, t = threadIdx.x;
    for (int i = t; i < nb; i += 256) hist[i] = 0;
    __syncthreads();
    int e0 = blk * chunk, e1 = min(e0 + chunk, E);
    for (int e = e0 + t; e < e1; e += 256) {
        int d = ei[E + e];
        atomicAdd(&deg[d], 1);          // 50K counters: uncontended
        atomicAdd(&hist[d >> 7], 1);    // LDS
    }
    __syncthreads();
    for (int i = t; i < nb; i += 256) bhist[i * NBLK + blk] = hist[i];
}

// ---------- 3. single-block: deg -> cursor (excl scan) ; then bucket boff scan ------
__global__ void __launch_bounds__(1024) k_scanboff(
    const int* __restrict__ deg, int* __restrict__ cursor,
    const int* __restrict__ bhist, int* __restrict__ boff, int N, int nb) {
    __shared__ int sb[1024];
    int t = threadIdx.x;
    int per = (N + 1023) >> 10;          // elems per thread (49 for N=50000)
    int base = t * per;
    // local sum
    int s = 0;
    for (int i = 0; i < per; i++) {
        int idx = base + i;
        if (idx < N) s += deg[idx];
    }
    sb[t] = s;
    __syncthreads();
    // Kogge-Stone inclusive scan over 1024 thread-sums
    for (int o = 1; o < 1024; o <<= 1) {
        int a = (t >= o) ? sb[t - o] : 0;
        __syncthreads();
        sb[t] += a;
        __syncthreads();
    }
    int run = sb[t] - s;                 // exclusive prefix of this thread's range
    for (int i = 0; i < per; i++) {
        int idx = base + i;
        if (idx < N) { cursor[idx] = run; run += deg[idx]; }
    }
    __syncthreads();                     // cursor visible within this workgroup
    // phase 2: per-bucket scan over chunks -> boff[blk*nb + b]
    for (int bkt = t; bkt < nb; bkt += 1024) {
        int run2 = cursor[bkt << 7];     // bucket start node < N by construction
        const int* row = bhist + bkt * NBLK;
#pragma unroll 8
        for (int blk = 0; blk < NBLK; blk++) {
            boff[blk * nb + bkt] = run2;
            run2 += row[blk];
        }
    }
}

// ---------- 4. placement: LDS cursors per chunk, dense per-(chunk,bucket) runs ------
__global__ void __launch_bounds__(256) k_bplace(
    const int* __restrict__ ei, const int* __restrict__ boff,
    unsigned int* __restrict__ packed, int E, int nb, int chunk) {
    __shared__ int lcur[MAXNB];
    int blk = blockIdx.x, t = threadIdx.x;
    for (int i = t; i < nb; i += 256) lcur[i] = boff[blk * nb + i];
    __syncthreads();
    int e0 = blk * chunk, e1 = min(e0 + chunk, E);
    for (int e = e0 + t; e < e1; e += 256) {
        int s = ei[e], d = ei[E + e];
        int pos = atomicAdd(&lcur[d >> 7], 1);      // LDS atomic
        packed[pos] = ((unsigned int)(d & 127) << 25) | (unsigned int)s;
    }
}

// ---------- 5. per-bucket placement into nbr (8 KB region, LDS node cursors) --------
__global__ void __launch_bounds__(256) k_bsort(
    const unsigned int* __restrict__ packed, const int* __restrict__ cursor,
    int* __restrict__ nbr, int N, int E) {
    __shared__ int lcur[128];
    int b = blockIdx.x, t = threadIdx.x;
    int node0 = b << 7;
    if (t < 128) {
        int node = node0 + t;
        lcur[t] = (node < N) ? cursor[node] : 0;
    }
    __syncthreads();
    int gstart = cursor[node0];
    int next = node0 + 128;
    int gend = (next < N) ? cursor[next] : E;
    for (int i = gstart + t; i < gend; i += 256) {
        unsigned int p = packed[i];
        int pos = atomicAdd(&lcur[p >> 25], 1);     // LDS atomic
        nbr[pos] = (int)(p & 0x1FFFFFFu);
    }
}

// ---------- 6. fused: CSR mean-gather -> MFMA GEMM -> LN -> gelu -> gate ----------
// Per block: 16 rows. Per wave: aggregate 4 nodes (4 rows per global_load_dwordx4:
// 16 lanes x 16B cover one 256B row), reduce across sub-groups via shfl_xor(16/32),
// write mean straight into LDS A-tile. h3 written to h3b (hb stays read-only here).
__global__ void __launch_bounds__(256) k_aggemm(
    const ushort_t* __restrict__ hb, const ushort_t* __restrict__ Wt,
    const float* __restrict__ bl, const float* __restrict__ lnw,
    const float* __restrict__ lnb, const float* __restrict__ gw,
    const float* __restrict__ gb, const int* __restrict__ deg,
    const int* __restrict__ cursor, const int* __restrict__ nbr,
    ushort_t* __restrict__ h3b, float* __restrict__ gate, int N) {
    __shared__ ushort_t A[16][264];   // [m][k], pad 264
    __shared__ float H2[16][132];
    int t = threadIdx.x;
    int row0 = blockIdx.x * 16;
    int w = t >> 6, l = t & 63;
    int sub = l >> 4, li = l & 15;    // sub: which row in a 4-row load group
    // ---- phase 0: aggregation + A-tile staging (per wave: rows w*4 .. w*4+3) ----
    for (int rr = 0; rr < 4; rr++) {
        int r = w * 4 + rr;
        int node = row0 + r; if (node >= N) node = N - 1;
        if (sub == 2) {               // stage own h row into right half of A
            bf16x8 hv = *(const bf16x8*)(hb + (size_t)node * 128 + li * 8);
            *(bf16x8*)&A[r][128 + li * 8] = hv;
        }
        int dg = deg[node];
        int st = cursor[node];
        float a0 = 0.f, a1 = 0.f, a2 = 0.f, a3 = 0.f;
        float a4 = 0.f, a5 = 0.f, a6 = 0.f, a7 = 0.f;
        for (int j = 0; j < dg; j += 8) {   // 8 rows per iter = 2 wide loads in flight
            int i0 = j + sub, i1 = j + 4 + sub;
            bf16x8 r0 = {0,0,0,0,0,0,0,0};
            bf16x8 r1 = {0,0,0,0,0,0,0,0};
            if (i0 < dg) {
                int s = nbr[st + i0];
                r0 = *(const bf16x8*)(hb + (size_t)s * 128 + li * 8);
            }
            if (i1 < dg) {
                int s = nbr[st + i1];
                r1 = *(const bf16x8*)(hb + (size_t)s * 128 + li * 8);
            }
            a0 += b2f((ushort_t)r0[0]) + b2f((ushort_t)r1[0]);
            a1 += b2f((ushort_t)r0[1]) + b2f((ushort_t)r1[1]);
            a2 += b2f((ushort_t)r0[2]) + b2f((ushort_t)r1[2]);
            a3 += b2f((ushort_t)r0[3]) + b2f((ushort_t)r1[3]);
            a4 += b2f((ushort_t)r0[4]) + b2f((ushort_t)r1[4]);
            a5 += b2f((ushort_t)r0[5]) + b2f((ushort_t)r1[5]);
            a6 += b2f((ushort_t)r0[6]) + b2f((ushort_t)r1[6]);
            a7 += b2f((ushort_t)r0[7]) + b2f((ushort_t)r1[7]);
        }
        // reduce across the 4 sub-groups (lanes l, l^16, l^32, l^48)
        a0 += __shfl_xor(a0, 16, 64); a0 += __shfl_xor(a0, 32, 64);
        a1 += __shfl_xor(a1, 16, 64); a1 += __shfl_xor(a1, 32, 64);
        a2 += __shfl_xor(a2, 16, 64); a2 += __shfl_xor(a2, 32, 64);
        a3 += __shfl_xor(a3, 16, 64); a3 += __shfl_xor(a3, 32, 64);
        a4 += __shfl_xor(a4, 16, 64); a4 += __shfl_xor(a4, 32, 64);
        a5 += __shfl_xor(a5, 16, 64); a5 += __shfl_xor(a5, 32, 64);
        a6 += __shfl_xor(a6, 16, 64); a6 += __shfl_xor(a6, 32, 64);
        a7 += __shfl_xor(a7, 16, 64); a7 += __shfl_xor(a7, 32, 64);
        if (sub == 0) {               // lanes 0..15 write the mean row (bf16)
            float inv = 1.0f / fmaxf((float)dg, 1.0f);
            bf16x8 ov;
            ov[0] = (short)f2b(a0 * inv); ov[1] = (short)f2b(a1 * inv);
            ov[2] = (short)f2b(a2 * inv); ov[3] = (short)f2b(a3 * inv);
            ov[4] = (short)f2b(a4 * inv); ov[5] = (short)f2b(a5 * inv);
            ov[6] = (short)f2b(a6 * inv); ov[7] = (short)f2b(a7 * inv);
            *(bf16x8*)&A[r][li * 8] = ov;
        }
    }
    __syncthreads();
    // ---- phase 1: MFMA over K=256 ----
    int m16 = l & 15, quad = l >> 4;
    int n0 = w * 32 + m16;
    int n1 = n0 + 16;
    floatx4 acc0 = {0.f, 0.f, 0.f, 0.f}, acc1 = {0.f, 0.f, 0.f, 0.f};
    for (int ks = 0; ks < 256; ks += 32) {
        bf16x8 a  = *(const bf16x8*)&A[m16][ks + quad * 8];
        bf16x8 b0 = *(const bf16x8*)(Wt + (size_t)n0 * 256 + ks + quad * 8);
        bf16x8 b1 = *(const bf16x8*)(Wt + (size_t)n1 * 256 + ks + quad * 8);
        acc0 = __builtin_amdgcn_mfma_f32_16x16x32_bf16(a, b0, acc0, 0, 0, 0);
        acc1 = __builtin_amdgcn_mfma_f32_16x16x32_bf16(a, b1, acc1, 0, 0, 0);
    }
#pragma unroll
    for (int i = 0; i < 4; i++) {
        H2[quad * 4 + i][n0] = acc0[i];
        H2[quad * 4 + i][n1] = acc1[i];
    }
    __syncthreads();
    // ---- phase 2: +bias, LN, gelu, gate; h3 -> h3b ----
    int d = l * 2;
    float bb0 = bl[d],  bb1 = bl[d + 1];
    float lw0 = lnw[d], lw1 = lnw[d + 1];
    float lb0 = lnb[d], lb1 = lnb[d + 1];
    float gw0 = gw[d],  gw1 = gw[d + 1];
    float gbias = gb[0];
#pragma unroll
    for (int rr = 0; rr < 4; rr++) {
        int r = w * 4 + rr;
        int row = row0 + r;
        if (row >= N) break;
        float v0 = H2[r][d] + bb0, v1 = H2[r][d + 1] + bb1;
        float s  = waveReduceSum(v0 + v1);
        float s2 = waveReduceSum(v0 * v0 + v1 * v1);
        float mu = s * (1.f / 128.f);
        float var = s2 * (1.f / 128.f) - mu * mu;
        float rstd = 1.0f / sqrtf(var + 1e-5f);
        float g0 = gelu_f((v0 - mu) * rstd * lw0 + lb0);
        float g1 = gelu_f((v1 - mu) * rstd * lw1 + lb1);
        float gp = waveReduceSum(g0 * gw0 + g1 * gw1);
        ushort2 ov; ov.x = f2b(g0); ov.y = f2b(g1);
        ((ushort2*)(h3b + (size_t)row * 128))[l] = ov;
        if (l == 0) gate[row] = gp + gbias;
    }
}

// ---------- 7. fused: segment bounds (binary search) + softmax pool + head ----------
__global__ void __launch_bounds__(128) k_attntail(
    const float* __restrict__ gate, const ushort_t* __restrict__ h3b,
    const int* __restrict__ batch,
    const float* __restrict__ text, const float* __restrict__ feats,
    const float* __restrict__ msgW, const float* __restrict__ msgb,
    const float* __restrict__ featW, const float* __restrict__ featb,
    const float* __restrict__ gwt, const float* __restrict__ mixw,
    const float* __restrict__ mixb, const float* __restrict__ fc1W,
    const float* __restrict__ fc1b,
    float* __restrict__ ge_out, float* __restrict__ attn_out,
    float* __restrict__ logits, int N, int G) {
    int g = blockIdx.x, t = threadIdx.x;
    __shared__ int sbound[2];
    __shared__ float wbuf[2];
    __shared__ float pbuf[128];
    __shared__ float txt[768];
    __shared__ float rbuf[4];
    if (t < 2) sbound[t] = lowerBound(batch, N, g + t);
    for (int i = t; i < 768; i += 128) txt[i] = text[(size_t)g * 768 + i];
    __syncthreads();
    int s0 = sbound[0], s1 = sbound[1];
    int lane = t & 63, wv = t >> 6;
    float acc = 0.f;
    if (s1 > s0) {                       // block-uniform branch
        float m = -3.0e38f;
        for (int i = s0 + t; i < s1; i += 128) m = fmaxf(m, gate[i]);
        m = waveReduceMax(m);
        if (lane == 0) wbuf[wv] = m;
        __syncthreads();
        m = fmaxf(wbuf[0], wbuf[1]);
        __syncthreads();
        float dsum = 0.f;
        for (int i = s0 + t; i < s1; i += 128) dsum += expf(gate[i] - m);
        dsum = waveReduceSum(dsum);
        if (lane == 0) wbuf[wv] = dsum;
        __syncthreads();
        float inv = 1.0f / (wbuf[0] + wbuf[1]);
        for (int base = s0; base < s1; base += 128) {
            int n = min(128, s1 - base);
            __syncthreads();
            if (t < n) {
                float p = expf(gate[base + t] - m) * inv;
                pbuf[t] = p;
                attn_out[base + t] = p;
            }
            __syncthreads();
            for (int j = 0; j < n; j++)
                acc += pbuf[j] * b2f(h3b[(size_t)(base + j) * 128 + t]);
        }
    }
    ge_out[(size_t)g * 128 + t] = acc;
    // ---- head ----
    float am = msgb[t];
    for (int k = 0; k < 768; k += 4) {
        float4 a = *(const float4*)&txt[k];
        am += a.x * msgW[(k + 0) * 128 + t] + a.y * msgW[(k + 1) * 128 + t]
            + a.z * msgW[(k + 2) * 128 + t] + a.w * msgW[(k + 3) * 128 + t];
    }
    float me = gelu_f(am);
    float af = featb[t];
#pragma unroll
    for (int k = 0; k < 14; k++) af += feats[g * 14 + k] * featW[k * 128 + t];
    float fe = gelu_f(af);
    float e0 = gwt[0] * acc;
    float ps = e0 + me + fe, ps2 = e0 * e0 + me * me + fe * fe;
    float r1 = waveReduceSum(ps), r2 = waveReduceSum(ps2);
    __syncthreads();
    if (lane == 0) { rbuf[wv] = r1; rbuf[2 + wv] = r2; }
    __syncthreads();
    float S = rbuf[0] + rbuf[1], S2 = rbuf[2] + rbuf[3];
    float mu = S * (1.f / 384.f);
    float var = S2 * (1.f / 384.f) - mu * mu;
    float rstd = 1.0f / sqrtf(var + 1e-5f);
    float n0 = (e0 - mu) * rstd * mixw[t]       + mixb[t];
    float n1 = (me - mu) * rstd * mixw[128 + t] + mixb[128 + t];
    float n2 = (fe - mu) * rstd * mixw[256 + t] + mixb[256 + t];
    float lp = n0 * fc1W[t] + n1 * fc1W[128 + t] + n2 * fc1W[256 + t];
    float r3 = waveReduceSum(lp);
    __syncthreads();
    if (lane == 0) rbuf[wv] = r3;
    __syncthreads();
    if (t == 0) logits[g] = rbuf[0] + rbuf[1] + fc1b[0];
}

// ---------- launch ----------
extern "C" void kernel_launch(void* const* d_in, const int* in_sizes, int n_in,
                              void* d_out, int out_size, void* d_ws, size_t ws_size,
                              hipStream_t stream) {
    const float* x     = (const float*)d_in[0];
    const int*   ei    = (const int*)d_in[1];
    const int*   batch = (const int*)d_in[2];
    const float* text  = (const float*)d_in[4];
    const float* feats = (const float*)d_in[5];
    const float* lnpw  = (const float*)d_in[6];
    const float* lnpb  = (const float*)d_in[7];
    const float* Wl    = (const float*)d_in[8];
    const float* bl    = (const float*)d_in[9];
    const float* Wr    = (const float*)d_in[10];
    const float* lncw  = (const float*)d_in[11];
    const float* lncb  = (const float*)d_in[12];
    const float* gatew = (const float*)d_in[13];
    const float* gateb = (const float*)d_in[14];
    const float* gwt   = (const float*)d_in[15];
    const float* msgW  = (const float*)d_in[16];
    const float* msgb  = (const float*)d_in[17];
    const float* featW = (const float*)d_in[18];
    const float* featb = (const float*)d_in[19];
    const float* mixw  = (const float*)d_in[20];
    const float* mixb  = (const float*)d_in[21];
    const float* fc1W  = (const float*)d_in[22];
    const float* fc1b  = (const float*)d_in[23];

    int N = in_sizes[0] / 128;
    int E = in_sizes[1] / 2;
    int G = in_sizes[4] / 768;

    char* wp = (char*)d_ws;
    auto alloc = [&](size_t bytes) -> char* {
        char* p = wp; wp += (bytes + 255) & ~(size_t)255; return p;
    };
    ushort_t* hb     = (ushort_t*)alloc((size_t)N * 128 * 2);   // h (bf16), read-only after prepln
    ushort_t* h3b    = (ushort_t*)alloc((size_t)N * 128 * 2);   // h3 (bf16) from aggemm
    ushort_t* Wt     = (ushort_t*)alloc(128 * 256 * 2);
    float*    gate   = (float*)alloc((size_t)N * 4);
    int*      deg    = (int*)alloc((size_t)N * 4);
    int*      cursor = (int*)alloc((size_t)N * 4);
    int*      nbr    = (int*)alloc((size_t)E * 4);
    unsigned int* packed = (unsigned int*)alloc((size_t)E * 4);

    int nb  = (N + 127) / 128;   // buckets of 128 nodes (391 for N=50000)
    int chunk = (E + NBLK - 1) / NBLK;

    int* bhist = (int*)alloc((size_t)nb * NBLK * 4);   // [b][blk]
    int* boff  = (int*)alloc((size_t)NBLK * nb * 4);   // [blk][b]

    // OUTPUTS fp32, flat in return order:
    float* logits_out = (float*)d_out;                 // [G, 1]
    float* ge_out     = logits_out + G;                // [G, 128]
    float* attn_out   = ge_out + (size_t)G * 128;      // [N, 1]

    k_prepln   <<<128 + (N + 3) / 4, 256, 0, stream>>>(x, lnpw, lnpb, Wl, Wr, Wt, hb, deg, N);
    k_deghist  <<<NBLK,              256, 0, stream>>>(ei, deg, bhist, E, nb, chunk);
    k_scanboff <<<1,                1024, 0, stream>>>(deg, cursor, bhist, boff, N, nb);
    k_bplace   <<<NBLK,              256, 0, stream>>>(ei, boff, packed, E, nb, chunk);
    k_bsort    <<<nb,                256, 0, stream>>>(packed, cursor, nbr, N, E);
    k_aggemm   <<<(N + 15) / 16,     256, 0, stream>>>(hb, Wt, bl, lncw, lncb, gatew, gateb,
                                                       deg, cursor, nbr, h3b, gate, N);
    k_attntail <<<G,                 128, 0, stream>>>(gate, h3b, batch, text, feats,
                                                       msgW, msgb, featW, featb, gwt,
                                                       mixw, mixb, fc1W, fc1b,
                                                       ge_out, attn_out, logits_out, N, G);
}

// Round 2
// 333.690 us; speedup vs baseline: 1.1155x; 1.1155x over previous
//
#include <hip/hip_runtime.h>

// Inputs: floats fp32, ints int32. Outputs fp32 (verified round 7).
// Round 18: fix the round-17 regression (single-block k_scanboff = 106 us,
// occupancy 0.17% -- one CU doing a latency chain).
//   - k_deghist additionally accumulates per-bucket edge totals btot[b]
//     (global atomicAdd of the LDS hist) and writes the hist TRANSPOSED
//     (bhistT[chunk][bucket], coalesced).
//   - k_cursor2 <<<nch,256>>>: each block redundantly reduces btot[0..2c)
//     for its chunk offset (no inter-block comms), then Kogge-Stone scans
//     its 256 deg values -> cursor. Replaces chunksum/chunkscan/cursor.
//   - bscan folded into k_bplace: block blk computes its own lcur column
//     from bhistT (coalesced rows) + cursor bucket starts. boff buffer gone.
//   - still 7 dispatches, but every kernel is wide-grid.

typedef unsigned short ushort_t;
typedef __attribute__((ext_vector_type(8))) short bf16x8;   // 8 bf16 (MFMA A/B frag)
typedef __attribute__((ext_vector_type(4))) float floatx4;  // MFMA C/D frag

#define NBLK 128      // edge chunks for hist/place
#define MAXNB 1024    // max buckets (N <= 131072)

// ---------- helpers ----------
__device__ __forceinline__ float b2f(ushort_t u) {
    union { unsigned int i; float f; } v; v.i = ((unsigned int)u) << 16; return v.f;
}
__device__ __forceinline__ ushort_t f2b(float f) {
    union { float f; unsigned int i; } v; v.f = f;
    unsigned int x = v.i;
    return (ushort_t)((x + 0x7FFFu + ((x >> 16) & 1u)) >> 16);   // RTNE
}
__device__ __forceinline__ float gelu_f(float x) {
    return 0.5f * x * (1.0f + erff(x * 0.70710678118654752440f)); // exact gelu
}
__device__ __forceinline__ float waveReduceSum(float v) {
#pragma unroll
    for (int o = 32; o; o >>= 1) v += __shfl_xor(v, o, 64);
    return v;
}
__device__ __forceinline__ int waveReduceSumI(int v) {
#pragma unroll
    for (int o = 32; o; o >>= 1) v += __shfl_xor(v, o, 64);
    return v;
}
__device__ __forceinline__ float waveReduceMax(float v) {
#pragma unroll
    for (int o = 32; o; o >>= 1) v = fmaxf(v, __shfl_xor(v, o, 64));
    return v;
}
__device__ __forceinline__ int lowerBound(const int* __restrict__ a, int n, int v) {
    int lo = 0, hi = n;
    while (lo < hi) { int mid = (lo + hi) >> 1; if (a[mid] < v) lo = mid + 1; else hi = mid; }
    return lo;
}

// ---------- 1. fused: Wt prep + btot zero (blocks 0..127) | LN1 + deg-zero ----------
__global__ void __launch_bounds__(256) k_prepln(
    const float* __restrict__ x, const float* __restrict__ w, const float* __restrict__ b,
    const float* __restrict__ Wl, const float* __restrict__ Wr,
    ushort_t* __restrict__ Wt, ushort_t* __restrict__ hb, int* __restrict__ deg,
    int* __restrict__ btot, int N, int nb) {
    int bid = blockIdx.x;
    if (bid < 128) {             // ---- prep role: Wt[n][k] = bf16 concat-T of Wl;Wr
        if (bid == 0) {          // zero bucket totals (nb <= MAXNB)
            for (int i = threadIdx.x; i < nb; i += 256) btot[i] = 0;
        }
        int id = bid * 256 + threadIdx.x;        // exactly 32768 threads
        int n = id >> 8, k = id & 255;
        float v = (k < 128) ? Wl[k * 128 + n] : Wr[(k - 128) * 128 + n];
        Wt[n * 256 + k] = f2b(v);
        return;
    }
    int lb = bid - 128;          // ---- ln1 role: 4 rows per block, 1 wave per row
    if (threadIdx.x < 4) {       // zero deg for this block's rows (replaces memset)
        int rz = lb * 4 + threadIdx.x;
        if (rz < N) deg[rz] = 0;
    }
    int row  = lb * 4 + (threadIdx.x >> 6);
    int lane = threadIdx.x & 63;
    if (row >= N) return;
    size_t base = (size_t)row * 128;
    float2 xv = ((const float2*)(x + base))[lane];
    float v0 = xv.x, v1 = xv.y;
    float s  = waveReduceSum(v0 + v1);
    float s2 = waveReduceSum(v0 * v0 + v1 * v1);
    float mu = s * (1.0f / 128.0f);
    float var = s2 * (1.0f / 128.0f) - mu * mu;
    float rstd = 1.0f / sqrtf(var + 1e-5f);
    int d = lane * 2;
    ushort2 ov;
    ov.x = f2b((v0 - mu) * rstd * w[d]     + b[d]);
    ov.y = f2b((v1 - mu) * rstd * w[d + 1] + b[d + 1]);
    ((ushort2*)(hb + base))[lane] = ov;
}

// ---------- 2. fused: deg[dst]++ + transposed bucket hist + bucket totals ----------
__global__ void __launch_bounds__(256) k_deghist(
    const int* __restrict__ ei, int* __restrict__ deg, int* __restrict__ bhistT,
    int* __restrict__ btot, int E, int nb, int chunk) {
    __shared__ int hist[MAXNB];
    int blk = blockIdx.x, t = threadIdx.x;
    for (int i = t; i < nb; i += 256) hist[i] = 0;
    __syncthreads();
    int e0 = blk * chunk, e1 = min(e0 + chunk, E);
    for (int e = e0 + t; e < e1; e += 256) {
        int d = ei[E + e];
        atomicAdd(&deg[d], 1);          // 50K counters: uncontended
        atomicAdd(&hist[d >> 7], 1);    // LDS
    }
    __syncthreads();
    for (int i = t; i < nb; i += 256) {
        int h = hist[i];
        bhistT[(size_t)blk * nb + i] = h;        // coalesced, transposed layout
        if (h) atomicAdd(&btot[i], h);           // global bucket totals
    }
}

// ---------- 3. cursor: per-chunk redundant offset reduce + Kogge-Stone scan ----------
__global__ void __launch_bounds__(256) k_cursor2(
    const int* __restrict__ deg, const int* __restrict__ btot,
    int* __restrict__ cursor, int N) {
    int c = blockIdx.x, t = threadIdx.x;
    __shared__ int sb[256];
    __shared__ int cw[4];
    // chunk offset = total edges to buckets < 2c (bucket=128 nodes, chunk=256)
    int lim = c * 2;
    int part = 0;
    for (int bkt = t; bkt < lim; bkt += 256) part += btot[bkt];
    part = waveReduceSumI(part);
    int lane = t & 63, wv = t >> 6;
    if (lane == 0) cw[wv] = part;
    // per-chunk element scan
    int i = c * 256 + t;
    int v = (i < N) ? deg[i] : 0;
    sb[t] = v;
    __syncthreads();
    for (int o = 1; o < 256; o <<= 1) {
        int a = (t >= o) ? sb[t - o] : 0;
        __syncthreads();
        sb[t] += a;
        __syncthreads();
    }
    int coff = cw[0] + cw[1] + cw[2] + cw[3];
    if (i < N) cursor[i] = sb[t] - v + coff;     // exclusive scan = row start
}

// ---------- 4. placement: per-block lcur column from bhistT, then place ----------
__global__ void __launch_bounds__(256) k_bplace(
    const int* __restrict__ ei, const int* __restrict__ bhistT,
    const int* __restrict__ cursor, unsigned int* __restrict__ packed,
    int E, int nb, int chunk) {
    __shared__ int lcur[MAXNB];
    int blk = blockIdx.x, t = threadIdx.x;
    // lcur[b] = cursor[b<<7] + sum_{c<blk} bhistT[c][b]   (coalesced rows)
    int a0 = 0, a1 = 0, a2 = 0, a3 = 0;
    int b0 = t, b1 = t + 256, b2 = t + 512, b3 = t + 768;
    if (b0 < nb) a0 = cursor[b0 << 7];
    if (b1 < nb) a1 = cursor[b1 << 7];
    if (b2 < nb) a2 = cursor[b2 << 7];
    if (b3 < nb) a3 = cursor[b3 << 7];
    for (int c = 0; c < blk; c++) {
        const int* row = bhistT + (size_t)c * nb;
        if (b0 < nb) a0 += row[b0];
        if (b1 < nb) a1 += row[b1];
        if (b2 < nb) a2 += row[b2];
        if (b3 < nb) a3 += row[b3];
    }
    if (b0 < nb) lcur[b0] = a0;
    if (b1 < nb) lcur[b1] = a1;
    if (b2 < nb) lcur[b2] = a2;
    if (b3 < nb) lcur[b3] = a3;
    __syncthreads();
    int e0 = blk * chunk, e1 = min(e0 + chunk, E);
    for (int e = e0 + t; e < e1; e += 256) {
        int s = ei[e], d = ei[E + e];
        int pos = atomicAdd(&lcur[d >> 7], 1);      // LDS atomic
        packed[pos] = ((unsigned int)(d & 127) << 25) | (unsigned int)s;
    }
}

// ---------- 5. per-bucket placement into nbr (8 KB region, LDS node cursors) --------
__global__ void __launch_bounds__(256) k_bsort(
    const unsigned int* __restrict__ packed, const int* __restrict__ cursor,
    int* __restrict__ nbr, int N, int E) {
    __shared__ int lcur[128];
    int b = blockIdx.x, t = threadIdx.x;
    int node0 = b << 7;
    if (t < 128) {
        int node = node0 + t;
        lcur[t] = (node < N) ? cursor[node] : 0;
    }
    __syncthreads();
    int gstart = cursor[node0];
    int next = node0 + 128;
    int gend = (next < N) ? cursor[next] : E;
    for (int i = gstart + t; i < gend; i += 256) {
        unsigned int p = packed[i];
        int pos = atomicAdd(&lcur[p >> 25], 1);     // LDS atomic
        nbr[pos] = (int)(p & 0x1FFFFFFu);
    }
}

// ---------- 6. fused: CSR mean-gather -> MFMA GEMM -> LN -> gelu -> gate ----------
__global__ void __launch_bounds__(256) k_aggemm(
    const ushort_t* __restrict__ hb, const ushort_t* __restrict__ Wt,
    const float* __restrict__ bl, const float* __restrict__ lnw,
    const float* __restrict__ lnb, const float* __restrict__ gw,
    const float* __restrict__ gb, const int* __restrict__ deg,
    const int* __restrict__ cursor, const int* __restrict__ nbr,
    ushort_t* __restrict__ h3b, float* __restrict__ gate, int N) {
    __shared__ ushort_t A[16][264];   // [m][k], pad 264
    __shared__ float H2[16][132];
    int t = threadIdx.x;
    int row0 = blockIdx.x * 16;
    int w = t >> 6, l = t & 63;
    int sub = l >> 4, li = l & 15;    // sub: which row in a 4-row load group
    // ---- phase 0: aggregation + A-tile staging (per wave: rows w*4 .. w*4+3) ----
    for (int rr = 0; rr < 4; rr++) {
        int r = w * 4 + rr;
        int node = row0 + r; if (node >= N) node = N - 1;
        if (sub == 2) {               // stage own h row into right half of A
            bf16x8 hv = *(const bf16x8*)(hb + (size_t)node * 128 + li * 8);
            *(bf16x8*)&A[r][128 + li * 8] = hv;
        }
        int dg = deg[node];
        int st = cursor[node];
        float a0 = 0.f, a1 = 0.f, a2 = 0.f, a3 = 0.f;
        float a4 = 0.f, a5 = 0.f, a6 = 0.f, a7 = 0.f;
        for (int j = 0; j < dg; j += 8) {   // 8 rows per iter = 2 wide loads in flight
            int i0 = j + sub, i1 = j + 4 + sub;
            bf16x8 r0 = {0,0,0,0,0,0,0,0};
            bf16x8 r1 = {0,0,0,0,0,0,0,0};
            if (i0 < dg) {
                int s = nbr[st + i0];
                r0 = *(const bf16x8*)(hb + (size_t)s * 128 + li * 8);
            }
            if (i1 < dg) {
                int s = nbr[st + i1];
                r1 = *(const bf16x8*)(hb + (size_t)s * 128 + li * 8);
            }
            a0 += b2f((ushort_t)r0[0]) + b2f((ushort_t)r1[0]);
            a1 += b2f((ushort_t)r0[1]) + b2f((ushort_t)r1[1]);
            a2 += b2f((ushort_t)r0[2]) + b2f((ushort_t)r1[2]);
            a3 += b2f((ushort_t)r0[3]) + b2f((ushort_t)r1[3]);
            a4 += b2f((ushort_t)r0[4]) + b2f((ushort_t)r1[4]);
            a5 += b2f((ushort_t)r0[5]) + b2f((ushort_t)r1[5]);
            a6 += b2f((ushort_t)r0[6]) + b2f((ushort_t)r1[6]);
            a7 += b2f((ushort_t)r0[7]) + b2f((ushort_t)r1[7]);
        }
        // reduce across the 4 sub-groups (lanes l, l^16, l^32, l^48)
        a0 += __shfl_xor(a0, 16, 64); a0 += __shfl_xor(a0, 32, 64);
        a1 += __shfl_xor(a1, 16, 64); a1 += __shfl_xor(a1, 32, 64);
        a2 += __shfl_xor(a2, 16, 64); a2 += __shfl_xor(a2, 32, 64);
        a3 += __shfl_xor(a3, 16, 64); a3 += __shfl_xor(a3, 32, 64);
        a4 += __shfl_xor(a4, 16, 64); a4 += __shfl_xor(a4, 32, 64);
        a5 += __shfl_xor(a5, 16, 64); a5 += __shfl_xor(a5, 32, 64);
        a6 += __shfl_xor(a6, 16, 64); a6 += __shfl_xor(a6, 32, 64);
        a7 += __shfl_xor(a7, 16, 64); a7 += __shfl_xor(a7, 32, 64);
        if (sub == 0) {               // lanes 0..15 write the mean row (bf16)
            float inv = 1.0f / fmaxf((float)dg, 1.0f);
            bf16x8 ov;
            ov[0] = (short)f2b(a0 * inv); ov[1] = (short)f2b(a1 * inv);
            ov[2] = (short)f2b(a2 * inv); ov[3] = (short)f2b(a3 * inv);
            ov[4] = (short)f2b(a4 * inv); ov[5] = (short)f2b(a5 * inv);
            ov[6] = (short)f2b(a6 * inv); ov[7] = (short)f2b(a7 * inv);
            *(bf16x8*)&A[r][li * 8] = ov;
        }
    }
    __syncthreads();
    // ---- phase 1: MFMA over K=256 ----
    int m16 = l & 15, quad = l >> 4;
    int n0 = w * 32 + m16;
    int n1 = n0 + 16;
    floatx4 acc0 = {0.f, 0.f, 0.f, 0.f}, acc1 = {0.f, 0.f, 0.f, 0.f};
    for (int ks = 0; ks < 256; ks += 32) {
        bf16x8 a  = *(const bf16x8*)&A[m16][ks + quad * 8];
        bf16x8 b0 = *(const bf16x8*)(Wt + (size_t)n0 * 256 + ks + quad * 8);
        bf16x8 b1 = *(const bf16x8*)(Wt + (size_t)n1 * 256 + ks + quad * 8);
        acc0 = __builtin_amdgcn_mfma_f32_16x16x32_bf16(a, b0, acc0, 0, 0, 0);
        acc1 = __builtin_amdgcn_mfma_f32_16x16x32_bf16(a, b1, acc1, 0, 0, 0);
    }
#pragma unroll
    for (int i = 0; i < 4; i++) {
        H2[quad * 4 + i][n0] = acc0[i];
        H2[quad * 4 + i][n1] = acc1[i];
    }
    __syncthreads();
    // ---- phase 2: +bias, LN, gelu, gate; h3 -> h3b ----
    int d = l * 2;
    float bb0 = bl[d],  bb1 = bl[d + 1];
    float lw0 = lnw[d], lw1 = lnw[d + 1];
    float lb0 = lnb[d], lb1 = lnb[d + 1];
    float gw0 = gw[d],  gw1 = gw[d + 1];
    float gbias = gb[0];
#pragma unroll
    for (int rr = 0; rr < 4; rr++) {
        int r = w * 4 + rr;
        int row = row0 + r;
        if (row >= N) break;
        float v0 = H2[r][d] + bb0, v1 = H2[r][d + 1] + bb1;
        float s  = waveReduceSum(v0 + v1);
        float s2 = waveReduceSum(v0 * v0 + v1 * v1);
        float mu = s * (1.f / 128.f);
        float var = s2 * (1.f / 128.f) - mu * mu;
        float rstd = 1.0f / sqrtf(var + 1e-5f);
        float g0 = gelu_f((v0 - mu) * rstd * lw0 + lb0);
        float g1 = gelu_f((v1 - mu) * rstd * lw1 + lb1);
        float gp = waveReduceSum(g0 * gw0 + g1 * gw1);
        ushort2 ov; ov.x = f2b(g0); ov.y = f2b(g1);
        ((ushort2*)(h3b + (size_t)row * 128))[l] = ov;
        if (l == 0) gate[row] = gp + gbias;
    }
}

// ---------- 7. fused: segment bounds (binary search) + softmax pool + head ----------
__global__ void __launch_bounds__(128) k_attntail(
    const float* __restrict__ gate, const ushort_t* __restrict__ h3b,
    const int* __restrict__ batch,
    const float* __restrict__ text, const float* __restrict__ feats,
    const float* __restrict__ msgW, const float* __restrict__ msgb,
    const float* __restrict__ featW, const float* __restrict__ featb,
    const float* __restrict__ gwt, const float* __restrict__ mixw,
    const float* __restrict__ mixb, const float* __restrict__ fc1W,
    const float* __restrict__ fc1b,
    float* __restrict__ ge_out, float* __restrict__ attn_out,
    float* __restrict__ logits, int N, int G) {
    int g = blockIdx.x, t = threadIdx.x;
    __shared__ int sbound[2];
    __shared__ float wbuf[2];
    __shared__ float pbuf[128];
    __shared__ float txt[768];
    __shared__ float rbuf[4];
    if (t < 2) sbound[t] = lowerBound(batch, N, g + t);
    for (int i = t; i < 768; i += 128) txt[i] = text[(size_t)g * 768 + i];
    __syncthreads();
    int s0 = sbound[0], s1 = sbound[1];
    int lane = t & 63, wv = t >> 6;
    float acc = 0.f;
    if (s1 > s0) {                       // block-uniform branch
        float m = -3.0e38f;
        for (int i = s0 + t; i < s1; i += 128) m = fmaxf(m, gate[i]);
        m = waveReduceMax(m);
        if (lane == 0) wbuf[wv] = m;
        __syncthreads();
        m = fmaxf(wbuf[0], wbuf[1]);
        __syncthreads();
        float dsum = 0.f;
        for (int i = s0 + t; i < s1; i += 128) dsum += expf(gate[i] - m);
        dsum = waveReduceSum(dsum);
        if (lane == 0) wbuf[wv] = dsum;
        __syncthreads();
        float inv = 1.0f / (wbuf[0] + wbuf[1]);
        for (int base = s0; base < s1; base += 128) {
            int n = min(128, s1 - base);
            __syncthreads();
            if (t < n) {
                float p = expf(gate[base + t] - m) * inv;
                pbuf[t] = p;
                attn_out[base + t] = p;
            }
            __syncthreads();
            for (int j = 0; j < n; j++)
                acc += pbuf[j] * b2f(h3b[(size_t)(base + j) * 128 + t]);
        }
    }
    ge_out[(size_t)g * 128 + t] = acc;
    // ---- head ----
    float am = msgb[t];
    for (int k = 0; k < 768; k += 4) {
        float4 a = *(const float4*)&txt[k];
        am += a.x * msgW[(k + 0) * 128 + t] + a.y * msgW[(k + 1) * 128 + t]
            + a.z * msgW[(k + 2) * 128 + t] + a.w * msgW[(k + 3) * 128 + t];
    }
    float me = gelu_f(am);
    float af = featb[t];
#pragma unroll
    for (int k = 0; k < 14; k++) af += feats[g * 14 + k] * featW[k * 128 + t];
    float fe = gelu_f(af);
    float e0 = gwt[0] * acc;
    float ps = e0 + me + fe, ps2 = e0 * e0 + me * me + fe * fe;
    float r1 = waveReduceSum(ps), r2 = waveReduceSum(ps2);
    __syncthreads();
    if (lane == 0) { rbuf[wv] = r1; rbuf[2 + wv] = r2; }
    __syncthreads();
    float S = rbuf[0] + rbuf[1], S2 = rbuf[2] + rbuf[3];
    float mu = S * (1.f / 384.f);
    float var = S2 * (1.f / 384.f) - mu * mu;
    float rstd = 1.0f / sqrtf(var + 1e-5f);
    float n0 = (e0 - mu) * rstd * mixw[t]       + mixb[t];
    float n1 = (me - mu) * rstd * mixw[128 + t] + mixb[128 + t];
    float n2 = (fe - mu) * rstd * mixw[256 + t] + mixb[256 + t];
    float lp = n0 * fc1W[t] + n1 * fc1W[128 + t] + n2 * fc1W[256 + t];
    float r3 = waveReduceSum(lp);
    __syncthreads();
    if (lane == 0) rbuf[wv] = r3;
    __syncthreads();
    if (t == 0) logits[g] = rbuf[0] + rbuf[1] + fc1b[0];
}

// ---------- launch ----------
extern "C" void kernel_launch(void* const* d_in, const int* in_sizes, int n_in,
                              void* d_out, int out_size, void* d_ws, size_t ws_size,
                              hipStream_t stream) {
    const float* x     = (const float*)d_in[0];
    const int*   ei    = (const int*)d_in[1];
    const int*   batch = (const int*)d_in[2];
    const float* text  = (const float*)d_in[4];
    const float* feats = (const float*)d_in[5];
    const float* lnpw  = (const float*)d_in[6];
    const float* lnpb  = (const float*)d_in[7];
    const float* Wl    = (const float*)d_in[8];
    const float* bl    = (const float*)d_in[9];
    const float* Wr    = (const float*)d_in[10];
    const float* lncw  = (const float*)d_in[11];
    const float* lncb  = (const float*)d_in[12];
    const float* gatew = (const float*)d_in[13];
    const float* gateb = (const float*)d_in[14];
    const float* gwt   = (const float*)d_in[15];
    const float* msgW  = (const float*)d_in[16];
    const float* msgb  = (const float*)d_in[17];
    const float* featW = (const float*)d_in[18];
    const float* featb = (const float*)d_in[19];
    const float* mixw  = (const float*)d_in[20];
    const float* mixb  = (const float*)d_in[21];
    const float* fc1W  = (const float*)d_in[22];
    const float* fc1b  = (const float*)d_in[23];

    int N = in_sizes[0] / 128;
    int E = in_sizes[1] / 2;
    int G = in_sizes[4] / 768;

    char* wp = (char*)d_ws;
    auto alloc = [&](size_t bytes) -> char* {
        char* p = wp; wp += (bytes + 255) & ~(size_t)255; return p;
    };
    ushort_t* hb     = (ushort_t*)alloc((size_t)N * 128 * 2);   // h (bf16), read-only after prepln
    ushort_t* h3b    = (ushort_t*)alloc((size_t)N * 128 * 2);   // h3 (bf16) from aggemm
    ushort_t* Wt     = (ushort_t*)alloc(128 * 256 * 2);
    float*    gate   = (float*)alloc((size_t)N * 4);
    int*      deg    = (int*)alloc((size_t)N * 4);
    int*      cursor = (int*)alloc((size_t)N * 4);
    int*      nbr    = (int*)alloc((size_t)E * 4);
    unsigned int* packed = (unsigned int*)alloc((size_t)E * 4);

    int nch = (N + 255) / 256;   // 196 chunks of 256 nodes
    int nb  = (N + 127) / 128;   // buckets of 128 nodes (391 for N=50000)
    int chunk = (E + NBLK - 1) / NBLK;

    int* bhistT = (int*)alloc((size_t)NBLK * nb * 4);  // [chunk][bucket], coalesced
    int* btot   = (int*)alloc((size_t)nb * 4);         // per-bucket edge totals

    // OUTPUTS fp32, flat in return order:
    float* logits_out = (float*)d_out;                 // [G, 1]
    float* ge_out     = logits_out + G;                // [G, 128]
    float* attn_out   = ge_out + (size_t)G * 128;      // [N, 1]

    k_prepln   <<<128 + (N + 3) / 4, 256, 0, stream>>>(x, lnpw, lnpb, Wl, Wr, Wt, hb,
                                                       deg, btot, N, nb);
    k_deghist  <<<NBLK,              256, 0, stream>>>(ei, deg, bhistT, btot, E, nb, chunk);
    k_cursor2  <<<nch,               256, 0, stream>>>(deg, btot, cursor, N);
    k_bplace   <<<NBLK,              256, 0, stream>>>(ei, bhistT, cursor, packed, E, nb, chunk);
    k_bsort    <<<nb,                256, 0, stream>>>(packed, cursor, nbr, N, E);
    k_aggemm   <<<(N + 15) / 16,     256, 0, stream>>>(hb, Wt, bl, lncw, lncb, gatew, gateb,
                                                       deg, cursor, nbr, h3b, gate, N);
    k_attntail <<<G,                 128, 0, stream>>>(gate, h3b, batch, text, feats,
                                                       msgW, msgb, featW, featb, gwt,
                                                       mixw, mixb, fc1W, fc1b,
                                                       ge_out, attn_out, logits_out, N, G);
}

// Round 3
// 325.670 us; speedup vs baseline: 1.1430x; 1.0246x over previous
//
#include <hip/hip_runtime.h>

// Inputs: floats fp32, ints int32. Outputs fp32 (verified round 7).
// Round 19: replace 4-kernel bucket sort with direct atomic CSR placement.
//   - k_count: atomicAdd(deg[dst]) 4 edges/thread (int4), 782 blocks.
//   - k_cursor3: block c redundantly reduces deg[0..c*256) for its offset
//     (no inter-block comm), KS-scans its 256 degs -> cursor + wcur copy.
//   - k_place: pos = atomicAdd(wcur[dst]); nbr[pos] = src. Order within a
//     node arbitrary (mean aggregation is order-independent).
//   - deghist/bplace/bsort + bhistT/btot/packed deleted. 6 wide dispatches.

typedef unsigned short ushort_t;
typedef __attribute__((ext_vector_type(8))) short bf16x8;   // 8 bf16 (MFMA A/B frag)
typedef __attribute__((ext_vector_type(4))) float floatx4;  // MFMA C/D frag

// ---------- helpers ----------
__device__ __forceinline__ float b2f(ushort_t u) {
    union { unsigned int i; float f; } v; v.i = ((unsigned int)u) << 16; return v.f;
}
__device__ __forceinline__ ushort_t f2b(float f) {
    union { float f; unsigned int i; } v; v.f = f;
    unsigned int x = v.i;
    return (ushort_t)((x + 0x7FFFu + ((x >> 16) & 1u)) >> 16);   // RTNE
}
__device__ __forceinline__ float gelu_f(float x) {
    return 0.5f * x * (1.0f + erff(x * 0.70710678118654752440f)); // exact gelu
}
__device__ __forceinline__ float waveReduceSum(float v) {
#pragma unroll
    for (int o = 32; o; o >>= 1) v += __shfl_xor(v, o, 64);
    return v;
}
__device__ __forceinline__ int waveReduceSumI(int v) {
#pragma unroll
    for (int o = 32; o; o >>= 1) v += __shfl_xor(v, o, 64);
    return v;
}
__device__ __forceinline__ float waveReduceMax(float v) {
#pragma unroll
    for (int o = 32; o; o >>= 1) v = fmaxf(v, __shfl_xor(v, o, 64));
    return v;
}
__device__ __forceinline__ int lowerBound(const int* __restrict__ a, int n, int v) {
    int lo = 0, hi = n;
    while (lo < hi) { int mid = (lo + hi) >> 1; if (a[mid] < v) lo = mid + 1; else hi = mid; }
    return lo;
}

// ---------- 1. fused: Wt prep (blocks 0..127) | LN1 + deg-zero (rest) ----------
__global__ void __launch_bounds__(256) k_prepln(
    const float* __restrict__ x, const float* __restrict__ w, const float* __restrict__ b,
    const float* __restrict__ Wl, const float* __restrict__ Wr,
    ushort_t* __restrict__ Wt, ushort_t* __restrict__ hb, int* __restrict__ deg, int N) {
    int bid = blockIdx.x;
    if (bid < 128) {             // ---- prep role: Wt[n][k] = bf16 concat-T of Wl;Wr
        int id = bid * 256 + threadIdx.x;        // exactly 32768 threads
        int n = id >> 8, k = id & 255;
        float v = (k < 128) ? Wl[k * 128 + n] : Wr[(k - 128) * 128 + n];
        Wt[n * 256 + k] = f2b(v);
        return;
    }
    int lb = bid - 128;          // ---- ln1 role: 4 rows per block, 1 wave per row
    if (threadIdx.x < 4) {       // zero deg for this block's rows (replaces memset)
        int rz = lb * 4 + threadIdx.x;
        if (rz < N) deg[rz] = 0;
    }
    int row  = lb * 4 + (threadIdx.x >> 6);
    int lane = threadIdx.x & 63;
    if (row >= N) return;
    size_t base = (size_t)row * 128;
    float2 xv = ((const float2*)(x + base))[lane];
    float v0 = xv.x, v1 = xv.y;
    float s  = waveReduceSum(v0 + v1);
    float s2 = waveReduceSum(v0 * v0 + v1 * v1);
    float mu = s * (1.0f / 128.0f);
    float var = s2 * (1.0f / 128.0f) - mu * mu;
    float rstd = 1.0f / sqrtf(var + 1e-5f);
    int d = lane * 2;
    ushort2 ov;
    ov.x = f2b((v0 - mu) * rstd * w[d]     + b[d]);
    ov.y = f2b((v1 - mu) * rstd * w[d + 1] + b[d + 1]);
    ((ushort2*)(hb + base))[lane] = ov;
}

// ---------- 2. degree count: 4 edges/thread, int4 loads ----------
__global__ void __launch_bounds__(256) k_count(
    const int* __restrict__ ei, int* __restrict__ deg, int E) {
    int i0 = (blockIdx.x * 256 + threadIdx.x) * 4;
    const int* dstp = ei + E;
    if (i0 + 3 < E) {
        int4 d4 = *(const int4*)(dstp + i0);
        atomicAdd(&deg[d4.x], 1);
        atomicAdd(&deg[d4.y], 1);
        atomicAdd(&deg[d4.z], 1);
        atomicAdd(&deg[d4.w], 1);
    } else {
        int e1 = min(i0 + 4, E);
        for (int i = i0; i < e1; i++) atomicAdd(&deg[dstp[i]], 1);
    }
}

// ---------- 3. cursor: redundant prefix reduce + Kogge-Stone scan -> cursor,wcur ----
__global__ void __launch_bounds__(256) k_cursor3(
    const int* __restrict__ deg, int* __restrict__ cursor, int* __restrict__ wcur, int N) {
    int c = blockIdx.x, t = threadIdx.x;
    __shared__ int sb[256];
    __shared__ int cw[4];
    // block offset = sum deg[0 .. c*256)  (coalesced, redundant per block)
    int lim = c << 8;
    int part = 0;
    for (int j = t; j < lim; j += 256) part += deg[j];
    part = waveReduceSumI(part);
    int lane = t & 63, wv = t >> 6;
    if (lane == 0) cw[wv] = part;
    // per-chunk element scan
    int i = (c << 8) + t;
    int v = (i < N) ? deg[i] : 0;
    sb[t] = v;
    __syncthreads();
    for (int o = 1; o < 256; o <<= 1) {
        int a = (t >= o) ? sb[t - o] : 0;
        __syncthreads();
        sb[t] += a;
        __syncthreads();
    }
    int coff = cw[0] + cw[1] + cw[2] + cw[3];
    if (i < N) {
        int cv = sb[t] - v + coff;     // exclusive scan = row start
        cursor[i] = cv;
        wcur[i]   = cv;
    }
}

// ---------- 4. direct placement: nbr[atomicAdd(wcur[dst])] = src ----------
__global__ void __launch_bounds__(256) k_place(
    const int* __restrict__ ei, int* __restrict__ wcur, int* __restrict__ nbr, int E) {
    int i0 = (blockIdx.x * 256 + threadIdx.x) * 4;
    if (i0 + 3 < E) {
        int4 s4 = *(const int4*)(ei + i0);
        int4 d4 = *(const int4*)(ei + E + i0);
        nbr[atomicAdd(&wcur[d4.x], 1)] = s4.x;
        nbr[atomicAdd(&wcur[d4.y], 1)] = s4.y;
        nbr[atomicAdd(&wcur[d4.z], 1)] = s4.z;
        nbr[atomicAdd(&wcur[d4.w], 1)] = s4.w;
    } else {
        int e1 = min(i0 + 4, E);
        for (int i = i0; i < e1; i++) {
            int s = ei[i], d = ei[E + i];
            nbr[atomicAdd(&wcur[d], 1)] = s;
        }
    }
}

// ---------- 5. fused: CSR mean-gather -> MFMA GEMM -> LN -> gelu -> gate ----------
__global__ void __launch_bounds__(256) k_aggemm(
    const ushort_t* __restrict__ hb, const ushort_t* __restrict__ Wt,
    const float* __restrict__ bl, const float* __restrict__ lnw,
    const float* __restrict__ lnb, const float* __restrict__ gw,
    const float* __restrict__ gb, const int* __restrict__ deg,
    const int* __restrict__ cursor, const int* __restrict__ nbr,
    ushort_t* __restrict__ h3b, float* __restrict__ gate, int N) {
    __shared__ ushort_t A[16][264];   // [m][k], pad 264
    __shared__ float H2[16][132];
    int t = threadIdx.x;
    int row0 = blockIdx.x * 16;
    int w = t >> 6, l = t & 63;
    int sub = l >> 4, li = l & 15;    // sub: which row in a 4-row load group
    // ---- phase 0: aggregation + A-tile staging (per wave: rows w*4 .. w*4+3) ----
    for (int rr = 0; rr < 4; rr++) {
        int r = w * 4 + rr;
        int node = row0 + r; if (node >= N) node = N - 1;
        if (sub == 2) {               // stage own h row into right half of A
            bf16x8 hv = *(const bf16x8*)(hb + (size_t)node * 128 + li * 8);
            *(bf16x8*)&A[r][128 + li * 8] = hv;
        }
        int dg = deg[node];
        int st = cursor[node];
        float a0 = 0.f, a1 = 0.f, a2 = 0.f, a3 = 0.f;
        float a4 = 0.f, a5 = 0.f, a6 = 0.f, a7 = 0.f;
        for (int j = 0; j < dg; j += 8) {   // 8 rows per iter = 2 wide loads in flight
            int i0 = j + sub, i1 = j + 4 + sub;
            bf16x8 r0 = {0,0,0,0,0,0,0,0};
            bf16x8 r1 = {0,0,0,0,0,0,0,0};
            if (i0 < dg) {
                int s = nbr[st + i0];
                r0 = *(const bf16x8*)(hb + (size_t)s * 128 + li * 8);
            }
            if (i1 < dg) {
                int s = nbr[st + i1];
                r1 = *(const bf16x8*)(hb + (size_t)s * 128 + li * 8);
            }
            a0 += b2f((ushort_t)r0[0]) + b2f((ushort_t)r1[0]);
            a1 += b2f((ushort_t)r0[1]) + b2f((ushort_t)r1[1]);
            a2 += b2f((ushort_t)r0[2]) + b2f((ushort_t)r1[2]);
            a3 += b2f((ushort_t)r0[3]) + b2f((ushort_t)r1[3]);
            a4 += b2f((ushort_t)r0[4]) + b2f((ushort_t)r1[4]);
            a5 += b2f((ushort_t)r0[5]) + b2f((ushort_t)r1[5]);
            a6 += b2f((ushort_t)r0[6]) + b2f((ushort_t)r1[6]);
            a7 += b2f((ushort_t)r0[7]) + b2f((ushort_t)r1[7]);
        }
        // reduce across the 4 sub-groups (lanes l, l^16, l^32, l^48)
        a0 += __shfl_xor(a0, 16, 64); a0 += __shfl_xor(a0, 32, 64);
        a1 += __shfl_xor(a1, 16, 64); a1 += __shfl_xor(a1, 32, 64);
        a2 += __shfl_xor(a2, 16, 64); a2 += __shfl_xor(a2, 32, 64);
        a3 += __shfl_xor(a3, 16, 64); a3 += __shfl_xor(a3, 32, 64);
        a4 += __shfl_xor(a4, 16, 64); a4 += __shfl_xor(a4, 32, 64);
        a5 += __shfl_xor(a5, 16, 64); a5 += __shfl_xor(a5, 32, 64);
        a6 += __shfl_xor(a6, 16, 64); a6 += __shfl_xor(a6, 32, 64);
        a7 += __shfl_xor(a7, 16, 64); a7 += __shfl_xor(a7, 32, 64);
        if (sub == 0) {               // lanes 0..15 write the mean row (bf16)
            float inv = 1.0f / fmaxf((float)dg, 1.0f);
            bf16x8 ov;
            ov[0] = (short)f2b(a0 * inv); ov[1] = (short)f2b(a1 * inv);
            ov[2] = (short)f2b(a2 * inv); ov[3] = (short)f2b(a3 * inv);
            ov[4] = (short)f2b(a4 * inv); ov[5] = (short)f2b(a5 * inv);
            ov[6] = (short)f2b(a6 * inv); ov[7] = (short)f2b(a7 * inv);
            *(bf16x8*)&A[r][li * 8] = ov;
        }
    }
    __syncthreads();
    // ---- phase 1: MFMA over K=256 ----
    int m16 = l & 15, quad = l >> 4;
    int n0 = w * 32 + m16;
    int n1 = n0 + 16;
    floatx4 acc0 = {0.f, 0.f, 0.f, 0.f}, acc1 = {0.f, 0.f, 0.f, 0.f};
    for (int ks = 0; ks < 256; ks += 32) {
        bf16x8 a  = *(const bf16x8*)&A[m16][ks + quad * 8];
        bf16x8 b0 = *(const bf16x8*)(Wt + (size_t)n0 * 256 + ks + quad * 8);
        bf16x8 b1 = *(const bf16x8*)(Wt + (size_t)n1 * 256 + ks + quad * 8);
        acc0 = __builtin_amdgcn_mfma_f32_16x16x32_bf16(a, b0, acc0, 0, 0, 0);
        acc1 = __builtin_amdgcn_mfma_f32_16x16x32_bf16(a, b1, acc1, 0, 0, 0);
    }
#pragma unroll
    for (int i = 0; i < 4; i++) {
        H2[quad * 4 + i][n0] = acc0[i];
        H2[quad * 4 + i][n1] = acc1[i];
    }
    __syncthreads();
    // ---- phase 2: +bias, LN, gelu, gate; h3 -> h3b ----
    int d = l * 2;
    float bb0 = bl[d],  bb1 = bl[d + 1];
    float lw0 = lnw[d], lw1 = lnw[d + 1];
    float lb0 = lnb[d], lb1 = lnb[d + 1];
    float gw0 = gw[d],  gw1 = gw[d + 1];
    float gbias = gb[0];
#pragma unroll
    for (int rr = 0; rr < 4; rr++) {
        int r = w * 4 + rr;
        int row = row0 + r;
        if (row >= N) break;
        float v0 = H2[r][d] + bb0, v1 = H2[r][d + 1] + bb1;
        float s  = waveReduceSum(v0 + v1);
        float s2 = waveReduceSum(v0 * v0 + v1 * v1);
        float mu = s * (1.f / 128.f);
        float var = s2 * (1.f / 128.f) - mu * mu;
        float rstd = 1.0f / sqrtf(var + 1e-5f);
        float g0 = gelu_f((v0 - mu) * rstd * lw0 + lb0);
        float g1 = gelu_f((v1 - mu) * rstd * lw1 + lb1);
        float gp = waveReduceSum(g0 * gw0 + g1 * gw1);
        ushort2 ov; ov.x = f2b(g0); ov.y = f2b(g1);
        ((ushort2*)(h3b + (size_t)row * 128))[l] = ov;
        if (l == 0) gate[row] = gp + gbias;
    }
}

// ---------- 6. fused: segment bounds (binary search) + softmax pool + head ----------
__global__ void __launch_bounds__(128) k_attntail(
    const float* __restrict__ gate, const ushort_t* __restrict__ h3b,
    const int* __restrict__ batch,
    const float* __restrict__ text, const float* __restrict__ feats,
    const float* __restrict__ msgW, const float* __restrict__ msgb,
    const float* __restrict__ featW, const float* __restrict__ featb,
    const float* __restrict__ gwt, const float* __restrict__ mixw,
    const float* __restrict__ mixb, const float* __restrict__ fc1W,
    const float* __restrict__ fc1b,
    float* __restrict__ ge_out, float* __restrict__ attn_out,
    float* __restrict__ logits, int N, int G) {
    int g = blockIdx.x, t = threadIdx.x;
    __shared__ int sbound[2];
    __shared__ float wbuf[2];
    __shared__ float pbuf[128];
    __shared__ float txt[768];
    __shared__ float rbuf[4];
    if (t < 2) sbound[t] = lowerBound(batch, N, g + t);
    for (int i = t; i < 768; i += 128) txt[i] = text[(size_t)g * 768 + i];
    __syncthreads();
    int s0 = sbound[0], s1 = sbound[1];
    int lane = t & 63, wv = t >> 6;
    float acc = 0.f;
    if (s1 > s0) {                       // block-uniform branch
        float m = -3.0e38f;
        for (int i = s0 + t; i < s1; i += 128) m = fmaxf(m, gate[i]);
        m = waveReduceMax(m);
        if (lane == 0) wbuf[wv] = m;
        __syncthreads();
        m = fmaxf(wbuf[0], wbuf[1]);
        __syncthreads();
        float dsum = 0.f;
        for (int i = s0 + t; i < s1; i += 128) dsum += expf(gate[i] - m);
        dsum = waveReduceSum(dsum);
        if (lane == 0) wbuf[wv] = dsum;
        __syncthreads();
        float inv = 1.0f / (wbuf[0] + wbuf[1]);
        for (int base = s0; base < s1; base += 128) {
            int n = min(128, s1 - base);
            __syncthreads();
            if (t < n) {
                float p = expf(gate[base + t] - m) * inv;
                pbuf[t] = p;
                attn_out[base + t] = p;
            }
            __syncthreads();
            for (int j = 0; j < n; j++)
                acc += pbuf[j] * b2f(h3b[(size_t)(base + j) * 128 + t]);
        }
    }
    ge_out[(size_t)g * 128 + t] = acc;
    // ---- head ----
    float am = msgb[t];
    for (int k = 0; k < 768; k += 4) {
        float4 a = *(const float4*)&txt[k];
        am += a.x * msgW[(k + 0) * 128 + t] + a.y * msgW[(k + 1) * 128 + t]
            + a.z * msgW[(k + 2) * 128 + t] + a.w * msgW[(k + 3) * 128 + t];
    }
    float me = gelu_f(am);
    float af = featb[t];
#pragma unroll
    for (int k = 0; k < 14; k++) af += feats[g * 14 + k] * featW[k * 128 + t];
    float fe = gelu_f(af);
    float e0 = gwt[0] * acc;
    float ps = e0 + me + fe, ps2 = e0 * e0 + me * me + fe * fe;
    float r1 = waveReduceSum(ps), r2 = waveReduceSum(ps2);
    __syncthreads();
    if (lane == 0) { rbuf[wv] = r1; rbuf[2 + wv] = r2; }
    __syncthreads();
    float S = rbuf[0] + rbuf[1], S2 = rbuf[2] + rbuf[3];
    float mu = S * (1.f / 384.f);
    float var = S2 * (1.f / 384.f) - mu * mu;
    float rstd = 1.0f / sqrtf(var + 1e-5f);
    float n0 = (e0 - mu) * rstd * mixw[t]       + mixb[t];
    float n1 = (me - mu) * rstd * mixw[128 + t] + mixb[128 + t];
    float n2 = (fe - mu) * rstd * mixw[256 + t] + mixb[256 + t];
    float lp = n0 * fc1W[t] + n1 * fc1W[128 + t] + n2 * fc1W[256 + t];
    float r3 = waveReduceSum(lp);
    __syncthreads();
    if (lane == 0) rbuf[wv] = r3;
    __syncthreads();
    if (t == 0) logits[g] = rbuf[0] + rbuf[1] + fc1b[0];
}

// ---------- launch ----------
extern "C" void kernel_launch(void* const* d_in, const int* in_sizes, int n_in,
                              void* d_out, int out_size, void* d_ws, size_t ws_size,
                              hipStream_t stream) {
    const float* x     = (const float*)d_in[0];
    const int*   ei    = (const int*)d_in[1];
    const int*   batch = (const int*)d_in[2];
    const float* text  = (const float*)d_in[4];
    const float* feats = (const float*)d_in[5];
    const float* lnpw  = (const float*)d_in[6];
    const float* lnpb  = (const float*)d_in[7];
    const float* Wl    = (const float*)d_in[8];
    const float* bl    = (const float*)d_in[9];
    const float* Wr    = (const float*)d_in[10];
    const float* lncw  = (const float*)d_in[11];
    const float* lncb  = (const float*)d_in[12];
    const float* gatew = (const float*)d_in[13];
    const float* gateb = (const float*)d_in[14];
    const float* gwt   = (const float*)d_in[15];
    const float* msgW  = (const float*)d_in[16];
    const float* msgb  = (const float*)d_in[17];
    const float* featW = (const float*)d_in[18];
    const float* featb = (const float*)d_in[19];
    const float* mixw  = (const float*)d_in[20];
    const float* mixb  = (const float*)d_in[21];
    const float* fc1W  = (const float*)d_in[22];
    const float* fc1b  = (const float*)d_in[23];

    int N = in_sizes[0] / 128;
    int E = in_sizes[1] / 2;
    int G = in_sizes[4] / 768;

    char* wp = (char*)d_ws;
    auto alloc = [&](size_t bytes) -> char* {
        char* p = wp; wp += (bytes + 255) & ~(size_t)255; return p;
    };
    ushort_t* hb     = (ushort_t*)alloc((size_t)N * 128 * 2);   // h (bf16), read-only after prepln
    ushort_t* h3b    = (ushort_t*)alloc((size_t)N * 128 * 2);   // h3 (bf16) from aggemm
    ushort_t* Wt     = (ushort_t*)alloc(128 * 256 * 2);
    float*    gate   = (float*)alloc((size_t)N * 4);
    int*      deg    = (int*)alloc((size_t)N * 4);
    int*      cursor = (int*)alloc((size_t)N * 4);
    int*      wcur   = (int*)alloc((size_t)N * 4);
    int*      nbr    = (int*)alloc((size_t)E * 4);

    int nch = (N + 255) / 256;   // 196 chunks of 256 nodes
    int eb  = (E + 1023) / 1024; // 4 edges/thread, 256 threads

    // OUTPUTS fp32, flat in return order:
    float* logits_out = (float*)d_out;                 // [G, 1]
    float* ge_out     = logits_out + G;                // [G, 128]
    float* attn_out   = ge_out + (size_t)G * 128;      // [N, 1]

    k_prepln   <<<128 + (N + 3) / 4, 256, 0, stream>>>(x, lnpw, lnpb, Wl, Wr, Wt, hb, deg, N);
    k_count    <<<eb,                256, 0, stream>>>(ei, deg, E);
    k_cursor3  <<<nch,               256, 0, stream>>>(deg, cursor, wcur, N);
    k_place    <<<eb,                256, 0, stream>>>(ei, wcur, nbr, E);
    k_aggemm   <<<(N + 15) / 16,     256, 0, stream>>>(hb, Wt, bl, lncw, lncb, gatew, gateb,
                                                       deg, cursor, nbr, h3b, gate, N);
    k_attntail <<<G,                 128, 0, stream>>>(gate, h3b, batch, text, feats,
                                                       msgW, msgb, featW, featb, gwt,
                                                       mixw, mixb, fc1W, fc1b,
                                                       ge_out, attn_out, logits_out, N, G);
}

// Round 4
// 316.828 us; speedup vs baseline: 1.1749x; 1.0279x over previous
//
#include <hip/hip_runtime.h>

// Inputs: floats fp32, ints int32. Outputs fp32 (verified round 7).
// Round 20: restore gather ILP inside fused aggemm.
//   - Each 16-lane subgroup owns ONE node (wave = 4 nodes concurrently):
//     8 independent 16B row-loads in flight per subgroup (32 rows/wave),
//     zero cross-lane shuffles, mean written straight into the A tile.
//   - Rest identical to round 19 (count/cursor3/place direct CSR).

typedef unsigned short ushort_t;
typedef __attribute__((ext_vector_type(8))) short bf16x8;   // 8 bf16 (MFMA A/B frag)
typedef __attribute__((ext_vector_type(4))) float floatx4;  // MFMA C/D frag

// ---------- helpers ----------
__device__ __forceinline__ float b2f(ushort_t u) {
    union { unsigned int i; float f; } v; v.i = ((unsigned int)u) << 16; return v.f;
}
__device__ __forceinline__ ushort_t f2b(float f) {
    union { float f; unsigned int i; } v; v.f = f;
    unsigned int x = v.i;
    return (ushort_t)((x + 0x7FFFu + ((x >> 16) & 1u)) >> 16);   // RTNE
}
__device__ __forceinline__ float gelu_f(float x) {
    return 0.5f * x * (1.0f + erff(x * 0.70710678118654752440f)); // exact gelu
}
__device__ __forceinline__ float waveReduceSum(float v) {
#pragma unroll
    for (int o = 32; o; o >>= 1) v += __shfl_xor(v, o, 64);
    return v;
}
__device__ __forceinline__ int waveReduceSumI(int v) {
#pragma unroll
    for (int o = 32; o; o >>= 1) v += __shfl_xor(v, o, 64);
    return v;
}
__device__ __forceinline__ float waveReduceMax(float v) {
#pragma unroll
    for (int o = 32; o; o >>= 1) v = fmaxf(v, __shfl_xor(v, o, 64));
    return v;
}
__device__ __forceinline__ int lowerBound(const int* __restrict__ a, int n, int v) {
    int lo = 0, hi = n;
    while (lo < hi) { int mid = (lo + hi) >> 1; if (a[mid] < v) lo = mid + 1; else hi = mid; }
    return lo;
}
__device__ __forceinline__ void acc8(float* a, const bf16x8& r) {
    a[0] += b2f((ushort_t)r[0]); a[1] += b2f((ushort_t)r[1]);
    a[2] += b2f((ushort_t)r[2]); a[3] += b2f((ushort_t)r[3]);
    a[4] += b2f((ushort_t)r[4]); a[5] += b2f((ushort_t)r[5]);
    a[6] += b2f((ushort_t)r[6]); a[7] += b2f((ushort_t)r[7]);
}

// ---------- 1. fused: Wt prep (blocks 0..127) | LN1 + deg-zero (rest) ----------
__global__ void __launch_bounds__(256) k_prepln(
    const float* __restrict__ x, const float* __restrict__ w, const float* __restrict__ b,
    const float* __restrict__ Wl, const float* __restrict__ Wr,
    ushort_t* __restrict__ Wt, ushort_t* __restrict__ hb, int* __restrict__ deg, int N) {
    int bid = blockIdx.x;
    if (bid < 128) {             // ---- prep role: Wt[n][k] = bf16 concat-T of Wl;Wr
        int id = bid * 256 + threadIdx.x;        // exactly 32768 threads
        int n = id >> 8, k = id & 255;
        float v = (k < 128) ? Wl[k * 128 + n] : Wr[(k - 128) * 128 + n];
        Wt[n * 256 + k] = f2b(v);
        return;
    }
    int lb = bid - 128;          // ---- ln1 role: 4 rows per block, 1 wave per row
    if (threadIdx.x < 4) {       // zero deg for this block's rows (replaces memset)
        int rz = lb * 4 + threadIdx.x;
        if (rz < N) deg[rz] = 0;
    }
    int row  = lb * 4 + (threadIdx.x >> 6);
    int lane = threadIdx.x & 63;
    if (row >= N) return;
    size_t base = (size_t)row * 128;
    float2 xv = ((const float2*)(x + base))[lane];
    float v0 = xv.x, v1 = xv.y;
    float s  = waveReduceSum(v0 + v1);
    float s2 = waveReduceSum(v0 * v0 + v1 * v1);
    float mu = s * (1.0f / 128.0f);
    float var = s2 * (1.0f / 128.0f) - mu * mu;
    float rstd = 1.0f / sqrtf(var + 1e-5f);
    int d = lane * 2;
    ushort2 ov;
    ov.x = f2b((v0 - mu) * rstd * w[d]     + b[d]);
    ov.y = f2b((v1 - mu) * rstd * w[d + 1] + b[d + 1]);
    ((ushort2*)(hb + base))[lane] = ov;
}

// ---------- 2. degree count: 4 edges/thread, int4 loads ----------
__global__ void __launch_bounds__(256) k_count(
    const int* __restrict__ ei, int* __restrict__ deg, int E) {
    int i0 = (blockIdx.x * 256 + threadIdx.x) * 4;
    const int* dstp = ei + E;
    if (i0 + 3 < E) {
        int4 d4 = *(const int4*)(dstp + i0);
        atomicAdd(&deg[d4.x], 1);
        atomicAdd(&deg[d4.y], 1);
        atomicAdd(&deg[d4.z], 1);
        atomicAdd(&deg[d4.w], 1);
    } else {
        int e1 = min(i0 + 4, E);
        for (int i = i0; i < e1; i++) atomicAdd(&deg[dstp[i]], 1);
    }
}

// ---------- 3. cursor: redundant prefix reduce + Kogge-Stone scan -> cursor,wcur ----
__global__ void __launch_bounds__(256) k_cursor3(
    const int* __restrict__ deg, int* __restrict__ cursor, int* __restrict__ wcur, int N) {
    int c = blockIdx.x, t = threadIdx.x;
    __shared__ int sb[256];
    __shared__ int cw[4];
    // block offset = sum deg[0 .. c*256)  (coalesced, redundant per block)
    int lim = c << 8;
    int part = 0;
    for (int j = t; j < lim; j += 256) part += deg[j];
    part = waveReduceSumI(part);
    int lane = t & 63, wv = t >> 6;
    if (lane == 0) cw[wv] = part;
    // per-chunk element scan
    int i = (c << 8) + t;
    int v = (i < N) ? deg[i] : 0;
    sb[t] = v;
    __syncthreads();
    for (int o = 1; o < 256; o <<= 1) {
        int a = (t >= o) ? sb[t - o] : 0;
        __syncthreads();
        sb[t] += a;
        __syncthreads();
    }
    int coff = cw[0] + cw[1] + cw[2] + cw[3];
    if (i < N) {
        int cv = sb[t] - v + coff;     // exclusive scan = row start
        cursor[i] = cv;
        wcur[i]   = cv;
    }
}

// ---------- 4. direct placement: nbr[atomicAdd(wcur[dst])] = src ----------
__global__ void __launch_bounds__(256) k_place(
    const int* __restrict__ ei, int* __restrict__ wcur, int* __restrict__ nbr, int E) {
    int i0 = (blockIdx.x * 256 + threadIdx.x) * 4;
    if (i0 + 3 < E) {
        int4 s4 = *(const int4*)(ei + i0);
        int4 d4 = *(const int4*)(ei + E + i0);
        nbr[atomicAdd(&wcur[d4.x], 1)] = s4.x;
        nbr[atomicAdd(&wcur[d4.y], 1)] = s4.y;
        nbr[atomicAdd(&wcur[d4.z], 1)] = s4.z;
        nbr[atomicAdd(&wcur[d4.w], 1)] = s4.w;
    } else {
        int e1 = min(i0 + 4, E);
        for (int i = i0; i < e1; i++) {
            int s = ei[i], d = ei[E + i];
            nbr[atomicAdd(&wcur[d], 1)] = s;
        }
    }
}

// ---------- 5. fused: CSR mean-gather -> MFMA GEMM -> LN -> gelu -> gate ----------
// Per block: 16 rows, 4 waves. Each 16-lane SUBGROUP owns one node: 16 lanes
// x 16B = one 256B row per load instr; 8 rows in flight (unrolled); no
// cross-lane reduction; bf16 mean written straight into the LDS A tile.
__global__ void __launch_bounds__(256) k_aggemm(
    const ushort_t* __restrict__ hb, const ushort_t* __restrict__ Wt,
    const float* __restrict__ bl, const float* __restrict__ lnw,
    const float* __restrict__ lnb, const float* __restrict__ gw,
    const float* __restrict__ gb, const int* __restrict__ deg,
    const int* __restrict__ cursor, const int* __restrict__ nbr,
    ushort_t* __restrict__ h3b, float* __restrict__ gate, int N) {
    __shared__ ushort_t A[16][264];   // [m][k], pad 264
    __shared__ float H2[16][132];
    int t = threadIdx.x;
    int row0 = blockIdx.x * 16;
    int w = t >> 6, l = t & 63;
    int sub = l >> 4, li = l & 15;
    // ---- phase 0: each subgroup aggregates its own node (row r = w*4+sub) ----
    {
        int r = w * 4 + sub;
        int node = row0 + r; if (node >= N) node = N - 1;
        // stage own h row into right half of A (16 lanes x 16B = 256B)
        bf16x8 hv = *(const bf16x8*)(hb + (size_t)node * 128 + li * 8);
        *(bf16x8*)&A[r][128 + li * 8] = hv;
        int dg = deg[node];
        int st = cursor[node];
        float a[8] = {0.f, 0.f, 0.f, 0.f, 0.f, 0.f, 0.f, 0.f};
        int j = 0;
        for (; j + 8 <= dg; j += 8) {        // 8 independent row loads in flight
            int s0 = nbr[st + j],     s1 = nbr[st + j + 1];
            int s2 = nbr[st + j + 2], s3 = nbr[st + j + 3];
            int s4 = nbr[st + j + 4], s5 = nbr[st + j + 5];
            int s6 = nbr[st + j + 6], s7 = nbr[st + j + 7];
            bf16x8 r0 = *(const bf16x8*)(hb + (size_t)s0 * 128 + li * 8);
            bf16x8 r1 = *(const bf16x8*)(hb + (size_t)s1 * 128 + li * 8);
            bf16x8 r2 = *(const bf16x8*)(hb + (size_t)s2 * 128 + li * 8);
            bf16x8 r3 = *(const bf16x8*)(hb + (size_t)s3 * 128 + li * 8);
            bf16x8 r4 = *(const bf16x8*)(hb + (size_t)s4 * 128 + li * 8);
            bf16x8 r5 = *(const bf16x8*)(hb + (size_t)s5 * 128 + li * 8);
            bf16x8 r6 = *(const bf16x8*)(hb + (size_t)s6 * 128 + li * 8);
            bf16x8 r7 = *(const bf16x8*)(hb + (size_t)s7 * 128 + li * 8);
            acc8(a, r0); acc8(a, r1); acc8(a, r2); acc8(a, r3);
            acc8(a, r4); acc8(a, r5); acc8(a, r6); acc8(a, r7);
        }
        for (; j + 4 <= dg; j += 4) {
            int s0 = nbr[st + j],     s1 = nbr[st + j + 1];
            int s2 = nbr[st + j + 2], s3 = nbr[st + j + 3];
            bf16x8 r0 = *(const bf16x8*)(hb + (size_t)s0 * 128 + li * 8);
            bf16x8 r1 = *(const bf16x8*)(hb + (size_t)s1 * 128 + li * 8);
            bf16x8 r2 = *(const bf16x8*)(hb + (size_t)s2 * 128 + li * 8);
            bf16x8 r3 = *(const bf16x8*)(hb + (size_t)s3 * 128 + li * 8);
            acc8(a, r0); acc8(a, r1); acc8(a, r2); acc8(a, r3);
        }
        for (; j < dg; j++) {
            int s = nbr[st + j];
            bf16x8 r0 = *(const bf16x8*)(hb + (size_t)s * 128 + li * 8);
            acc8(a, r0);
        }
        float inv = 1.0f / fmaxf((float)dg, 1.0f);
        bf16x8 ov;
        ov[0] = (short)f2b(a[0] * inv); ov[1] = (short)f2b(a[1] * inv);
        ov[2] = (short)f2b(a[2] * inv); ov[3] = (short)f2b(a[3] * inv);
        ov[4] = (short)f2b(a[4] * inv); ov[5] = (short)f2b(a[5] * inv);
        ov[6] = (short)f2b(a[6] * inv); ov[7] = (short)f2b(a[7] * inv);
        *(bf16x8*)&A[r][li * 8] = ov;
    }
    __syncthreads();
    // ---- phase 1: MFMA over K=256 ----
    int m16 = l & 15, quad = l >> 4;
    int n0 = w * 32 + m16;
    int n1 = n0 + 16;
    floatx4 acc0 = {0.f, 0.f, 0.f, 0.f}, acc1 = {0.f, 0.f, 0.f, 0.f};
    for (int ks = 0; ks < 256; ks += 32) {
        bf16x8 a  = *(const bf16x8*)&A[m16][ks + quad * 8];
        bf16x8 b0 = *(const bf16x8*)(Wt + (size_t)n0 * 256 + ks + quad * 8);
        bf16x8 b1 = *(const bf16x8*)(Wt + (size_t)n1 * 256 + ks + quad * 8);
        acc0 = __builtin_amdgcn_mfma_f32_16x16x32_bf16(a, b0, acc0, 0, 0, 0);
        acc1 = __builtin_amdgcn_mfma_f32_16x16x32_bf16(a, b1, acc1, 0, 0, 0);
    }
#pragma unroll
    for (int i = 0; i < 4; i++) {
        H2[quad * 4 + i][n0] = acc0[i];
        H2[quad * 4 + i][n1] = acc1[i];
    }
    __syncthreads();
    // ---- phase 2: +bias, LN, gelu, gate; h3 -> h3b ----
    int d = l * 2;
    float bb0 = bl[d],  bb1 = bl[d + 1];
    float lw0 = lnw[d], lw1 = lnw[d + 1];
    float lb0 = lnb[d], lb1 = lnb[d + 1];
    float gw0 = gw[d],  gw1 = gw[d + 1];
    float gbias = gb[0];
#pragma unroll
    for (int rr = 0; rr < 4; rr++) {
        int r = w * 4 + rr;
        int row = row0 + r;
        if (row >= N) break;
        float v0 = H2[r][d] + bb0, v1 = H2[r][d + 1] + bb1;
        float s  = waveReduceSum(v0 + v1);
        float s2 = waveReduceSum(v0 * v0 + v1 * v1);
        float mu = s * (1.f / 128.f);
        float var = s2 * (1.f / 128.f) - mu * mu;
        float rstd = 1.0f / sqrtf(var + 1e-5f);
        float g0 = gelu_f((v0 - mu) * rstd * lw0 + lb0);
        float g1 = gelu_f((v1 - mu) * rstd * lw1 + lb1);
        float gp = waveReduceSum(g0 * gw0 + g1 * gw1);
        ushort2 ov; ov.x = f2b(g0); ov.y = f2b(g1);
        ((ushort2*)(h3b + (size_t)row * 128))[l] = ov;
        if (l == 0) gate[row] = gp + gbias;
    }
}

// ---------- 6. fused: segment bounds (binary search) + softmax pool + head ----------
__global__ void __launch_bounds__(128) k_attntail(
    const float* __restrict__ gate, const ushort_t* __restrict__ h3b,
    const int* __restrict__ batch,
    const float* __restrict__ text, const float* __restrict__ feats,
    const float* __restrict__ msgW, const float* __restrict__ msgb,
    const float* __restrict__ featW, const float* __restrict__ featb,
    const float* __restrict__ gwt, const float* __restrict__ mixw,
    const float* __restrict__ mixb, const float* __restrict__ fc1W,
    const float* __restrict__ fc1b,
    float* __restrict__ ge_out, float* __restrict__ attn_out,
    float* __restrict__ logits, int N, int G) {
    int g = blockIdx.x, t = threadIdx.x;
    __shared__ int sbound[2];
    __shared__ float wbuf[2];
    __shared__ float pbuf[128];
    __shared__ float txt[768];
    __shared__ float rbuf[4];
    if (t < 2) sbound[t] = lowerBound(batch, N, g + t);
    for (int i = t; i < 768; i += 128) txt[i] = text[(size_t)g * 768 + i];
    __syncthreads();
    int s0 = sbound[0], s1 = sbound[1];
    int lane = t & 63, wv = t >> 6;
    float acc = 0.f;
    if (s1 > s0) {                       // block-uniform branch
        float m = -3.0e38f;
        for (int i = s0 + t; i < s1; i += 128) m = fmaxf(m, gate[i]);
        m = waveReduceMax(m);
        if (lane == 0) wbuf[wv] = m;
        __syncthreads();
        m = fmaxf(wbuf[0], wbuf[1]);
        __syncthreads();
        float dsum = 0.f;
        for (int i = s0 + t; i < s1; i += 128) dsum += expf(gate[i] - m);
        dsum = waveReduceSum(dsum);
        if (lane == 0) wbuf[wv] = dsum;
        __syncthreads();
        float inv = 1.0f / (wbuf[0] + wbuf[1]);
        for (int base = s0; base < s1; base += 128) {
            int n = min(128, s1 - base);
            __syncthreads();
            if (t < n) {
                float p = expf(gate[base + t] - m) * inv;
                pbuf[t] = p;
                attn_out[base + t] = p;
            }
            __syncthreads();
            for (int j = 0; j < n; j++)
                acc += pbuf[j] * b2f(h3b[(size_t)(base + j) * 128 + t]);
        }
    }
    ge_out[(size_t)g * 128 + t] = acc;
    // ---- head ----
    float am = msgb[t];
    for (int k = 0; k < 768; k += 4) {
        float4 a = *(const float4*)&txt[k];
        am += a.x * msgW[(k + 0) * 128 + t] + a.y * msgW[(k + 1) * 128 + t]
            + a.z * msgW[(k + 2) * 128 + t] + a.w * msgW[(k + 3) * 128 + t];
    }
    float me = gelu_f(am);
    float af = featb[t];
#pragma unroll
    for (int k = 0; k < 14; k++) af += feats[g * 14 + k] * featW[k * 128 + t];
    float fe = gelu_f(af);
    float e0 = gwt[0] * acc;
    float ps = e0 + me + fe, ps2 = e0 * e0 + me * me + fe * fe;
    float r1 = waveReduceSum(ps), r2 = waveReduceSum(ps2);
    __syncthreads();
    if (lane == 0) { rbuf[wv] = r1; rbuf[2 + wv] = r2; }
    __syncthreads();
    float S = rbuf[0] + rbuf[1], S2 = rbuf[2] + rbuf[3];
    float mu = S * (1.f / 384.f);
    float var = S2 * (1.f / 384.f) - mu * mu;
    float rstd = 1.0f / sqrtf(var + 1e-5f);
    float n0 = (e0 - mu) * rstd * mixw[t]       + mixb[t];
    float n1 = (me - mu) * rstd * mixw[128 + t] + mixb[128 + t];
    float n2 = (fe - mu) * rstd * mixw[256 + t] + mixb[256 + t];
    float lp = n0 * fc1W[t] + n1 * fc1W[128 + t] + n2 * fc1W[256 + t];
    float r3 = waveReduceSum(lp);
    __syncthreads();
    if (lane == 0) rbuf[wv] = r3;
    __syncthreads();
    if (t == 0) logits[g] = rbuf[0] + rbuf[1] + fc1b[0];
}

// ---------- launch ----------
extern "C" void kernel_launch(void* const* d_in, const int* in_sizes, int n_in,
                              void* d_out, int out_size, void* d_ws, size_t ws_size,
                              hipStream_t stream) {
    const float* x     = (const float*)d_in[0];
    const int*   ei    = (const int*)d_in[1];
    const int*   batch = (const int*)d_in[2];
    const float* text  = (const float*)d_in[4];
    const float* feats = (const float*)d_in[5];
    const float* lnpw  = (const float*)d_in[6];
    const float* lnpb  = (const float*)d_in[7];
    const float* Wl    = (const float*)d_in[8];
    const float* bl    = (const float*)d_in[9];
    const float* Wr    = (const float*)d_in[10];
    const float* lncw  = (const float*)d_in[11];
    const float* lncb  = (const float*)d_in[12];
    const float* gatew = (const float*)d_in[13];
    const float* gateb = (const float*)d_in[14];
    const float* gwt   = (const float*)d_in[15];
    const float* msgW  = (const float*)d_in[16];
    const float* msgb  = (const float*)d_in[17];
    const float* featW = (const float*)d_in[18];
    const float* featb = (const float*)d_in[19];
    const float* mixw  = (const float*)d_in[20];
    const float* mixb  = (const float*)d_in[21];
    const float* fc1W  = (const float*)d_in[22];
    const float* fc1b  = (const float*)d_in[23];

    int N = in_sizes[0] / 128;
    int E = in_sizes[1] / 2;
    int G = in_sizes[4] / 768;

    char* wp = (char*)d_ws;
    auto alloc = [&](size_t bytes) -> char* {
        char* p = wp; wp += (bytes + 255) & ~(size_t)255; return p;
    };
    ushort_t* hb     = (ushort_t*)alloc((size_t)N * 128 * 2);   // h (bf16), read-only after prepln
    ushort_t* h3b    = (ushort_t*)alloc((size_t)N * 128 * 2);   // h3 (bf16) from aggemm
    ushort_t* Wt     = (ushort_t*)alloc(128 * 256 * 2);
    float*    gate   = (float*)alloc((size_t)N * 4);
    int*      deg    = (int*)alloc((size_t)N * 4);
    int*      cursor = (int*)alloc((size_t)N * 4);
    int*      wcur   = (int*)alloc((size_t)N * 4);
    int*      nbr    = (int*)alloc((size_t)E * 4);

    int nch = (N + 255) / 256;   // 196 chunks of 256 nodes
    int eb  = (E + 1023) / 1024; // 4 edges/thread, 256 threads

    // OUTPUTS fp32, flat in return order:
    float* logits_out = (float*)d_out;                 // [G, 1]
    float* ge_out     = logits_out + G;                // [G, 128]
    float* attn_out   = ge_out + (size_t)G * 128;      // [N, 1]

    k_prepln   <<<128 + (N + 3) / 4, 256, 0, stream>>>(x, lnpw, lnpb, Wl, Wr, Wt, hb, deg, N);
    k_count    <<<eb,                256, 0, stream>>>(ei, deg, E);
    k_cursor3  <<<nch,               256, 0, stream>>>(deg, cursor, wcur, N);
    k_place    <<<eb,                256, 0, stream>>>(ei, wcur, nbr, E);
    k_aggemm   <<<(N + 15) / 16,     256, 0, stream>>>(hb, Wt, bl, lncw, lncb, gatew, gateb,
                                                       deg, cursor, nbr, h3b, gate, N);
    k_attntail <<<G,                 128, 0, stream>>>(gate, h3b, batch, text, feats,
                                                       msgW, msgb, featW, featb, gwt,
                                                       mixw, mixb, fc1W, fc1b,
                                                       ge_out, attn_out, logits_out, N, G);
}

// Round 5
// 306.512 us; speedup vs baseline: 1.2144x; 1.0337x over previous
//
#include <hip/hip_runtime.h>

// Inputs: floats fp32, ints int32. Outputs fp32 (verified round 7).
// Round 21: overlap independent work + place ILP.
//   - k_cpl: count (8 edges/thread, blocks 0..ebc) | Wt prep (next 128) |
//     LN1 (rest) merged into ONE dispatch -- count's atomic latency hidden
//     under LN bandwidth work. deg zeroed by hipMemsetAsync up front.
//   - k_place: 8 edges/thread, all 8 atomics issued before the 8 stores
//     (2x memory-level parallelism, half the waves).
//   - aggemm/attntail unchanged (clean attribution).

typedef unsigned short ushort_t;
typedef __attribute__((ext_vector_type(8))) short bf16x8;   // 8 bf16 (MFMA A/B frag)
typedef __attribute__((ext_vector_type(4))) float floatx4;  // MFMA C/D frag

// ---------- helpers ----------
__device__ __forceinline__ float b2f(ushort_t u) {
    union { unsigned int i; float f; } v; v.i = ((unsigned int)u) << 16; return v.f;
}
__device__ __forceinline__ ushort_t f2b(float f) {
    union { float f; unsigned int i; } v; v.f = f;
    unsigned int x = v.i;
    return (ushort_t)((x + 0x7FFFu + ((x >> 16) & 1u)) >> 16);   // RTNE
}
__device__ __forceinline__ float gelu_f(float x) {
    return 0.5f * x * (1.0f + erff(x * 0.70710678118654752440f)); // exact gelu
}
__device__ __forceinline__ float waveReduceSum(float v) {
#pragma unroll
    for (int o = 32; o; o >>= 1) v += __shfl_xor(v, o, 64);
    return v;
}
__device__ __forceinline__ int waveReduceSumI(int v) {
#pragma unroll
    for (int o = 32; o; o >>= 1) v += __shfl_xor(v, o, 64);
    return v;
}
__device__ __forceinline__ float waveReduceMax(float v) {
#pragma unroll
    for (int o = 32; o; o >>= 1) v = fmaxf(v, __shfl_xor(v, o, 64));
    return v;
}
__device__ __forceinline__ int lowerBound(const int* __restrict__ a, int n, int v) {
    int lo = 0, hi = n;
    while (lo < hi) { int mid = (lo + hi) >> 1; if (a[mid] < v) lo = mid + 1; else hi = mid; }
    return lo;
}
__device__ __forceinline__ void acc8(float* a, const bf16x8& r) {
    a[0] += b2f((ushort_t)r[0]); a[1] += b2f((ushort_t)r[1]);
    a[2] += b2f((ushort_t)r[2]); a[3] += b2f((ushort_t)r[3]);
    a[4] += b2f((ushort_t)r[4]); a[5] += b2f((ushort_t)r[5]);
    a[6] += b2f((ushort_t)r[6]); a[7] += b2f((ushort_t)r[7]);
}

// ---------- 1. fused: edge count (0..ebc) | Wt prep (+128) | LN1 (rest) ----------
__global__ void __launch_bounds__(256) k_cpl(
    const float* __restrict__ x, const float* __restrict__ w, const float* __restrict__ b,
    const float* __restrict__ Wl, const float* __restrict__ Wr,
    const int* __restrict__ ei, int* __restrict__ deg,
    ushort_t* __restrict__ Wt, ushort_t* __restrict__ hb, int N, int E, int ebc) {
    int bid = blockIdx.x;
    if (bid < ebc) {             // ---- count role: 8 edges/thread, int4 x2
        int i0 = (bid * 256 + threadIdx.x) * 8;
        const int* dstp = ei + E;
        if (i0 + 7 < E) {
            int4 a = *(const int4*)(dstp + i0);
            int4 c = *(const int4*)(dstp + i0 + 4);
            atomicAdd(&deg[a.x], 1); atomicAdd(&deg[a.y], 1);
            atomicAdd(&deg[a.z], 1); atomicAdd(&deg[a.w], 1);
            atomicAdd(&deg[c.x], 1); atomicAdd(&deg[c.y], 1);
            atomicAdd(&deg[c.z], 1); atomicAdd(&deg[c.w], 1);
        } else {
            int e1 = min(i0 + 8, E);
            for (int i = i0; i < e1; i++) atomicAdd(&deg[dstp[i]], 1);
        }
        return;
    }
    bid -= ebc;
    if (bid < 128) {             // ---- prep role: Wt[n][k] = bf16 concat-T of Wl;Wr
        int id = bid * 256 + threadIdx.x;        // exactly 32768 threads
        int n = id >> 8, k = id & 255;
        float v = (k < 128) ? Wl[k * 128 + n] : Wr[(k - 128) * 128 + n];
        Wt[n * 256 + k] = f2b(v);
        return;
    }
    int lb = bid - 128;          // ---- ln1 role: 4 rows per block, 1 wave per row
    int row  = lb * 4 + (threadIdx.x >> 6);
    int lane = threadIdx.x & 63;
    if (row >= N) return;
    size_t base = (size_t)row * 128;
    float2 xv = ((const float2*)(x + base))[lane];
    float v0 = xv.x, v1 = xv.y;
    float s  = waveReduceSum(v0 + v1);
    float s2 = waveReduceSum(v0 * v0 + v1 * v1);
    float mu = s * (1.0f / 128.0f);
    float var = s2 * (1.0f / 128.0f) - mu * mu;
    float rstd = 1.0f / sqrtf(var + 1e-5f);
    int d = lane * 2;
    ushort2 ov;
    ov.x = f2b((v0 - mu) * rstd * w[d]     + b[d]);
    ov.y = f2b((v1 - mu) * rstd * w[d + 1] + b[d + 1]);
    ((ushort2*)(hb + base))[lane] = ov;
}

// ---------- 2. cursor: redundant prefix reduce + Kogge-Stone scan -> cursor,wcur ----
__global__ void __launch_bounds__(256) k_cursor3(
    const int* __restrict__ deg, int* __restrict__ cursor, int* __restrict__ wcur, int N) {
    int c = blockIdx.x, t = threadIdx.x;
    __shared__ int sb[256];
    __shared__ int cw[4];
    // block offset = sum deg[0 .. c*256)  (coalesced, redundant per block)
    int lim = c << 8;
    int part = 0;
    for (int j = t; j < lim; j += 256) part += deg[j];
    part = waveReduceSumI(part);
    int lane = t & 63, wv = t >> 6;
    if (lane == 0) cw[wv] = part;
    // per-chunk element scan
    int i = (c << 8) + t;
    int v = (i < N) ? deg[i] : 0;
    sb[t] = v;
    __syncthreads();
    for (int o = 1; o < 256; o <<= 1) {
        int a = (t >= o) ? sb[t - o] : 0;
        __syncthreads();
        sb[t] += a;
        __syncthreads();
    }
    int coff = cw[0] + cw[1] + cw[2] + cw[3];
    if (i < N) {
        int cv = sb[t] - v + coff;     // exclusive scan = row start
        cursor[i] = cv;
        wcur[i]   = cv;
    }
}

// ---------- 3. direct placement: 8 edges/thread, atomics batched before stores ------
__global__ void __launch_bounds__(256) k_place(
    const int* __restrict__ ei, int* __restrict__ wcur, int* __restrict__ nbr, int E) {
    int i0 = (blockIdx.x * 256 + threadIdx.x) * 8;
    if (i0 + 7 < E) {
        int4 s0 = *(const int4*)(ei + i0);
        int4 s1 = *(const int4*)(ei + i0 + 4);
        int4 d0 = *(const int4*)(ei + E + i0);
        int4 d1 = *(const int4*)(ei + E + i0 + 4);
        int p0 = atomicAdd(&wcur[d0.x], 1);
        int p1 = atomicAdd(&wcur[d0.y], 1);
        int p2 = atomicAdd(&wcur[d0.z], 1);
        int p3 = atomicAdd(&wcur[d0.w], 1);
        int p4 = atomicAdd(&wcur[d1.x], 1);
        int p5 = atomicAdd(&wcur[d1.y], 1);
        int p6 = atomicAdd(&wcur[d1.z], 1);
        int p7 = atomicAdd(&wcur[d1.w], 1);
        nbr[p0] = s0.x; nbr[p1] = s0.y; nbr[p2] = s0.z; nbr[p3] = s0.w;
        nbr[p4] = s1.x; nbr[p5] = s1.y; nbr[p6] = s1.z; nbr[p7] = s1.w;
    } else {
        int e1 = min(i0 + 8, E);
        for (int i = i0; i < e1; i++) {
            int s = ei[i], d = ei[E + i];
            nbr[atomicAdd(&wcur[d], 1)] = s;
        }
    }
}

// ---------- 4. fused: CSR mean-gather -> MFMA GEMM -> LN -> gelu -> gate ----------
__global__ void __launch_bounds__(256) k_aggemm(
    const ushort_t* __restrict__ hb, const ushort_t* __restrict__ Wt,
    const float* __restrict__ bl, const float* __restrict__ lnw,
    const float* __restrict__ lnb, const float* __restrict__ gw,
    const float* __restrict__ gb, const int* __restrict__ deg,
    const int* __restrict__ cursor, const int* __restrict__ nbr,
    ushort_t* __restrict__ h3b, float* __restrict__ gate, int N) {
    __shared__ ushort_t A[16][264];   // [m][k], pad 264
    __shared__ float H2[16][132];
    int t = threadIdx.x;
    int row0 = blockIdx.x * 16;
    int w = t >> 6, l = t & 63;
    int sub = l >> 4, li = l & 15;
    // ---- phase 0: each subgroup aggregates its own node (row r = w*4+sub) ----
    {
        int r = w * 4 + sub;
        int node = row0 + r; if (node >= N) node = N - 1;
        bf16x8 hv = *(const bf16x8*)(hb + (size_t)node * 128 + li * 8);
        *(bf16x8*)&A[r][128 + li * 8] = hv;
        int dg = deg[node];
        int st = cursor[node];
        float a[8] = {0.f, 0.f, 0.f, 0.f, 0.f, 0.f, 0.f, 0.f};
        int j = 0;
        for (; j + 8 <= dg; j += 8) {        // 8 independent row loads in flight
            int s0 = nbr[st + j],     s1 = nbr[st + j + 1];
            int s2 = nbr[st + j + 2], s3 = nbr[st + j + 3];
            int s4 = nbr[st + j + 4], s5 = nbr[st + j + 5];
            int s6 = nbr[st + j + 6], s7 = nbr[st + j + 7];
            bf16x8 r0 = *(const bf16x8*)(hb + (size_t)s0 * 128 + li * 8);
            bf16x8 r1 = *(const bf16x8*)(hb + (size_t)s1 * 128 + li * 8);
            bf16x8 r2 = *(const bf16x8*)(hb + (size_t)s2 * 128 + li * 8);
            bf16x8 r3 = *(const bf16x8*)(hb + (size_t)s3 * 128 + li * 8);
            bf16x8 r4 = *(const bf16x8*)(hb + (size_t)s4 * 128 + li * 8);
            bf16x8 r5 = *(const bf16x8*)(hb + (size_t)s5 * 128 + li * 8);
            bf16x8 r6 = *(const bf16x8*)(hb + (size_t)s6 * 128 + li * 8);
            bf16x8 r7 = *(const bf16x8*)(hb + (size_t)s7 * 128 + li * 8);
            acc8(a, r0); acc8(a, r1); acc8(a, r2); acc8(a, r3);
            acc8(a, r4); acc8(a, r5); acc8(a, r6); acc8(a, r7);
        }
        for (; j + 4 <= dg; j += 4) {
            int s0 = nbr[st + j],     s1 = nbr[st + j + 1];
            int s2 = nbr[st + j + 2], s3 = nbr[st + j + 3];
            bf16x8 r0 = *(const bf16x8*)(hb + (size_t)s0 * 128 + li * 8);
            bf16x8 r1 = *(const bf16x8*)(hb + (size_t)s1 * 128 + li * 8);
            bf16x8 r2 = *(const bf16x8*)(hb + (size_t)s2 * 128 + li * 8);
            bf16x8 r3 = *(const bf16x8*)(hb + (size_t)s3 * 128 + li * 8);
            acc8(a, r0); acc8(a, r1); acc8(a, r2); acc8(a, r3);
        }
        for (; j < dg; j++) {
            int s = nbr[st + j];
            bf16x8 r0 = *(const bf16x8*)(hb + (size_t)s * 128 + li * 8);
            acc8(a, r0);
        }
        float inv = 1.0f / fmaxf((float)dg, 1.0f);
        bf16x8 ov;
        ov[0] = (short)f2b(a[0] * inv); ov[1] = (short)f2b(a[1] * inv);
        ov[2] = (short)f2b(a[2] * inv); ov[3] = (short)f2b(a[3] * inv);
        ov[4] = (short)f2b(a[4] * inv); ov[5] = (short)f2b(a[5] * inv);
        ov[6] = (short)f2b(a[6] * inv); ov[7] = (short)f2b(a[7] * inv);
        *(bf16x8*)&A[r][li * 8] = ov;
    }
    __syncthreads();
    // ---- phase 1: MFMA over K=256 ----
    int m16 = l & 15, quad = l >> 4;
    int n0 = w * 32 + m16;
    int n1 = n0 + 16;
    floatx4 acc0 = {0.f, 0.f, 0.f, 0.f}, acc1 = {0.f, 0.f, 0.f, 0.f};
    for (int ks = 0; ks < 256; ks += 32) {
        bf16x8 a  = *(const bf16x8*)&A[m16][ks + quad * 8];
        bf16x8 b0 = *(const bf16x8*)(Wt + (size_t)n0 * 256 + ks + quad * 8);
        bf16x8 b1 = *(const bf16x8*)(Wt + (size_t)n1 * 256 + ks + quad * 8);
        acc0 = __builtin_amdgcn_mfma_f32_16x16x32_bf16(a, b0, acc0, 0, 0, 0);
        acc1 = __builtin_amdgcn_mfma_f32_16x16x32_bf16(a, b1, acc1, 0, 0, 0);
    }
#pragma unroll
    for (int i = 0; i < 4; i++) {
        H2[quad * 4 + i][n0] = acc0[i];
        H2[quad * 4 + i][n1] = acc1[i];
    }
    __syncthreads();
    // ---- phase 2: +bias, LN, gelu, gate; h3 -> h3b ----
    int d = l * 2;
    float bb0 = bl[d],  bb1 = bl[d + 1];
    float lw0 = lnw[d], lw1 = lnw[d + 1];
    float lb0 = lnb[d], lb1 = lnb[d + 1];
    float gw0 = gw[d],  gw1 = gw[d + 1];
    float gbias = gb[0];
#pragma unroll
    for (int rr = 0; rr < 4; rr++) {
        int r = w * 4 + rr;
        int row = row0 + r;
        if (row >= N) break;
        float v0 = H2[r][d] + bb0, v1 = H2[r][d + 1] + bb1;
        float s  = waveReduceSum(v0 + v1);
        float s2 = waveReduceSum(v0 * v0 + v1 * v1);
        float mu = s * (1.f / 128.f);
        float var = s2 * (1.f / 128.f) - mu * mu;
        float rstd = 1.0f / sqrtf(var + 1e-5f);
        float g0 = gelu_f((v0 - mu) * rstd * lw0 + lb0);
        float g1 = gelu_f((v1 - mu) * rstd * lw1 + lb1);
        float gp = waveReduceSum(g0 * gw0 + g1 * gw1);
        ushort2 ov; ov.x = f2b(g0); ov.y = f2b(g1);
        ((ushort2*)(h3b + (size_t)row * 128))[l] = ov;
        if (l == 0) gate[row] = gp + gbias;
    }
}

// ---------- 5. fused: segment bounds (binary search) + softmax pool + head ----------
__global__ void __launch_bounds__(128) k_attntail(
    const float* __restrict__ gate, const ushort_t* __restrict__ h3b,
    const int* __restrict__ batch,
    const float* __restrict__ text, const float* __restrict__ feats,
    const float* __restrict__ msgW, const float* __restrict__ msgb,
    const float* __restrict__ featW, const float* __restrict__ featb,
    const float* __restrict__ gwt, const float* __restrict__ mixw,
    const float* __restrict__ mixb, const float* __restrict__ fc1W,
    const float* __restrict__ fc1b,
    float* __restrict__ ge_out, float* __restrict__ attn_out,
    float* __restrict__ logits, int N, int G) {
    int g = blockIdx.x, t = threadIdx.x;
    __shared__ int sbound[2];
    __shared__ float wbuf[2];
    __shared__ float pbuf[128];
    __shared__ float txt[768];
    __shared__ float rbuf[4];
    if (t < 2) sbound[t] = lowerBound(batch, N, g + t);
    for (int i = t; i < 768; i += 128) txt[i] = text[(size_t)g * 768 + i];
    __syncthreads();
    int s0 = sbound[0], s1 = sbound[1];
    int lane = t & 63, wv = t >> 6;
    float acc = 0.f;
    if (s1 > s0) {                       // block-uniform branch
        float m = -3.0e38f;
        for (int i = s0 + t; i < s1; i += 128) m = fmaxf(m, gate[i]);
        m = waveReduceMax(m);
        if (lane == 0) wbuf[wv] = m;
        __syncthreads();
        m = fmaxf(wbuf[0], wbuf[1]);
        __syncthreads();
        float dsum = 0.f;
        for (int i = s0 + t; i < s1; i += 128) dsum += expf(gate[i] - m);
        dsum = waveReduceSum(dsum);
        if (lane == 0) wbuf[wv] = dsum;
        __syncthreads();
        float inv = 1.0f / (wbuf[0] + wbuf[1]);
        for (int base = s0; base < s1; base += 128) {
            int n = min(128, s1 - base);
            __syncthreads();
            if (t < n) {
                float p = expf(gate[base + t] - m) * inv;
                pbuf[t] = p;
                attn_out[base + t] = p;
            }
            __syncthreads();
            for (int j = 0; j < n; j++)
                acc += pbuf[j] * b2f(h3b[(size_t)(base + j) * 128 + t]);
        }
    }
    ge_out[(size_t)g * 128 + t] = acc;
    // ---- head ----
    float am = msgb[t];
    for (int k = 0; k < 768; k += 4) {
        float4 a = *(const float4*)&txt[k];
        am += a.x * msgW[(k + 0) * 128 + t] + a.y * msgW[(k + 1) * 128 + t]
            + a.z * msgW[(k + 2) * 128 + t] + a.w * msgW[(k + 3) * 128 + t];
    }
    float me = gelu_f(am);
    float af = featb[t];
#pragma unroll
    for (int k = 0; k < 14; k++) af += feats[g * 14 + k] * featW[k * 128 + t];
    float fe = gelu_f(af);
    float e0 = gwt[0] * acc;
    float ps = e0 + me + fe, ps2 = e0 * e0 + me * me + fe * fe;
    float r1 = waveReduceSum(ps), r2 = waveReduceSum(ps2);
    __syncthreads();
    if (lane == 0) { rbuf[wv] = r1; rbuf[2 + wv] = r2; }
    __syncthreads();
    float S = rbuf[0] + rbuf[1], S2 = rbuf[2] + rbuf[3];
    float mu = S * (1.f / 384.f);
    float var = S2 * (1.f / 384.f) - mu * mu;
    float rstd = 1.0f / sqrtf(var + 1e-5f);
    float n0 = (e0 - mu) * rstd * mixw[t]       + mixb[t];
    float n1 = (me - mu) * rstd * mixw[128 + t] + mixb[128 + t];
    float n2 = (fe - mu) * rstd * mixw[256 + t] + mixb[256 + t];
    float lp = n0 * fc1W[t] + n1 * fc1W[128 + t] + n2 * fc1W[256 + t];
    float r3 = waveReduceSum(lp);
    __syncthreads();
    if (lane == 0) rbuf[wv] = r3;
    __syncthreads();
    if (t == 0) logits[g] = rbuf[0] + rbuf[1] + fc1b[0];
}

// ---------- launch ----------
extern "C" void kernel_launch(void* const* d_in, const int* in_sizes, int n_in,
                              void* d_out, int out_size, void* d_ws, size_t ws_size,
                              hipStream_t stream) {
    const float* x     = (const float*)d_in[0];
    const int*   ei    = (const int*)d_in[1];
    const int*   batch = (const int*)d_in[2];
    const float* text  = (const float*)d_in[4];
    const float* feats = (const float*)d_in[5];
    const float* lnpw  = (const float*)d_in[6];
    const float* lnpb  = (const float*)d_in[7];
    const float* Wl    = (const float*)d_in[8];
    const float* bl    = (const float*)d_in[9];
    const float* Wr    = (const float*)d_in[10];
    const float* lncw  = (const float*)d_in[11];
    const float* lncb  = (const float*)d_in[12];
    const float* gatew = (const float*)d_in[13];
    const float* gateb = (const float*)d_in[14];
    const float* gwt   = (const float*)d_in[15];
    const float* msgW  = (const float*)d_in[16];
    const float* msgb  = (const float*)d_in[17];
    const float* featW = (const float*)d_in[18];
    const float* featb = (const float*)d_in[19];
    const float* mixw  = (const float*)d_in[20];
    const float* mixb  = (const float*)d_in[21];
    const float* fc1W  = (const float*)d_in[22];
    const float* fc1b  = (const float*)d_in[23];

    int N = in_sizes[0] / 128;
    int E = in_sizes[1] / 2;
    int G = in_sizes[4] / 768;

    char* wp = (char*)d_ws;
    auto alloc = [&](size_t bytes) -> char* {
        char* p = wp; wp += (bytes + 255) & ~(size_t)255; return p;
    };
    ushort_t* hb     = (ushort_t*)alloc((size_t)N * 128 * 2);   // h (bf16), read-only after cpl
    ushort_t* h3b    = (ushort_t*)alloc((size_t)N * 128 * 2);   // h3 (bf16) from aggemm
    ushort_t* Wt     = (ushort_t*)alloc(128 * 256 * 2);
    float*    gate   = (float*)alloc((size_t)N * 4);
    int*      deg    = (int*)alloc((size_t)N * 4);
    int*      cursor = (int*)alloc((size_t)N * 4);
    int*      wcur   = (int*)alloc((size_t)N * 4);
    int*      nbr    = (int*)alloc((size_t)E * 4);

    int nch = (N + 255) / 256;    // 196 chunks of 256 nodes
    int ebc = (E + 2047) / 2048;  // 8 edges/thread, 256 threads (391)

    // OUTPUTS fp32, flat in return order:
    float* logits_out = (float*)d_out;                 // [G, 1]
    float* ge_out     = logits_out + G;                // [G, 128]
    float* attn_out   = ge_out + (size_t)G * 128;      // [N, 1]

    hipMemsetAsync(deg, 0, (size_t)N * 4, stream);
    k_cpl      <<<ebc + 128 + (N + 3) / 4, 256, 0, stream>>>(
                                                   x, lnpw, lnpb, Wl, Wr, ei, deg,
                                                   Wt, hb, N, E, ebc);
    k_cursor3  <<<nch,               256, 0, stream>>>(deg, cursor, wcur, N);
    k_place    <<<ebc,               256, 0, stream>>>(ei, wcur, nbr, E);
    k_aggemm   <<<(N + 15) / 16,     256, 0, stream>>>(hb, Wt, bl, lncw, lncb, gatew, gateb,
                                                       deg, cursor, nbr, h3b, gate, N);
    k_attntail <<<G,                 128, 0, stream>>>(gate, h3b, batch, text, feats,
                                                       msgW, msgb, featW, featb, gwt,
                                                       mixw, mixb, fc1W, fc1b,
                                                       ge_out, attn_out, logits_out, N, G);
}